// Round 4
// baseline (33299.509 us; speedup 1.0000x reference)
//
#include <hip/hip_runtime.h>
#include <stdint.h>

// ---------------------------------------------------------------------------
// SimpleRNN: bidirectional LSTM encoder (S=256) + autoregressive decoder (T=128)
// B=128, D=256, H=1024. Persistent kernels + hand-rolled grid barriers.
// ROUND 4: 3-term split-bf16 GEMM — BOTH weights and activations split into
// hi+lo bf16 planes (Wh*Ah + Wh*Al + Wl*Ah), giving ~2^-17 per-step relative
// error. Weights staged directly from original f32 tensors (gate-interleave
// via addressing). f32 accum + f32 gate math. Minimal workspace (~3.3 MB).
// ---------------------------------------------------------------------------

typedef __attribute__((ext_vector_type(8))) short bfx8;
typedef __attribute__((ext_vector_type(4))) float f32x4;
typedef __attribute__((ext_vector_type(4))) unsigned short u16x4;
typedef unsigned short ushort_t;

#define NWG 256

__device__ __forceinline__ unsigned short f2bf(float f){
  unsigned u = __float_as_uint(f);
  u += 0x7FFFu + ((u >> 16) & 1u);          // round-to-nearest-even
  return (unsigned short)(u >> 16);
}
__device__ __forceinline__ float bf2f(unsigned short h){
  return __uint_as_float(((unsigned)h) << 16);
}
__device__ __forceinline__ float sigm(float x){ return 1.f/(1.f + __expf(-x)); }
__device__ __forceinline__ float tanh_(float x){ return 1.f - 2.f/(__expf(2.f*x) + 1.f); }

#define MFMA(a,b,c) __builtin_amdgcn_mfma_f32_16x16x32_bf16((a),(b),(c),0,0,0)

__device__ __forceinline__ void grid_barrier(unsigned* cnt, unsigned expect){
  __syncthreads();                       // all waves' stores drained
  if (threadIdx.x == 0){
    __threadfence();                     // release: agent scope
    atomicAdd(cnt, 1u);
    while (__hip_atomic_load(cnt, __ATOMIC_ACQUIRE, __HIP_MEMORY_SCOPE_AGENT) < expect){
      __builtin_amdgcn_s_sleep(2);
    }
    __threadfence();                     // acquire: invalidate stale caches
  }
  __syncthreads();
}

// 8 consecutive f32 -> split hi+lo bf16 planes (RNE both)
__device__ __forceinline__ void cvt8s(const float* p, bfx8& hi, bfx8& lo){
  f32x4 a = *(const f32x4*)p;
  f32x4 b = *(const f32x4*)(p + 4);
#pragma unroll
  for (int j = 0; j < 4; ++j){
    unsigned short h0 = f2bf(a[j]);
    unsigned short h1 = f2bf(b[j]);
    hi[j]   = (short)h0; lo[j]   = (short)f2bf(a[j] - bf2f(h0));
    hi[4+j] = (short)h1; lo[4+j] = (short)f2bf(b[j] - bf2f(h1));
  }
}

// ---------------------------------------------------------------------------
// One LSTM cell step: WG owns 64 gate-interleaved W-rows' (16 neurons) x 64
// batches. g = [x|h] @ W'.T via 3-term split product. D[r'][b] orientation:
// lane's 4 acc regs = gates {i,f,g,o} of one (n,b).
// W' row r'=4n+q read from original f32: Wih[q*1024+n][k] / Whh[q*1024+n][k-256]
// ---------------------------------------------------------------------------
template<int ENC>
__device__ __forceinline__ void cell_step(
    const float* __restrict__ Wih,   // [4096][256] f32 (this dir)
    const float* __restrict__ Whh,   // [4096][1024] f32 (this dir)
    const float* __restrict__ bias,  // [4096] f32 (this dir, original order)
    const float* __restrict__ xsl,   // ENC: x + tt*256 (row stride 65536)
    const ushort_t* __restrict__ iph,// DEC: [128][256] hi plane
    const ushort_t* __restrict__ ipl,// DEC: lo plane
    const ushort_t* __restrict__ hh, // h hi (base + dir*1024), row stride 2048
    const ushort_t* __restrict__ hl, // h lo
    ushort_t*       __restrict__ outh,
    ushort_t*       __restrict__ outl,
    float*          __restrict__ Cst,// [1024][128] f32 c-state (this dir)
    int r0, int n0, int b0,
    ushort_t (*sWh)[72], ushort_t (*sWl)[72],
    ushort_t (*sAh)[72], ushort_t (*sAl)[72])
{
  const int tid  = threadIdx.x;
  const int lane = tid & 63;
  const int wv   = tid >> 6;
  const int wm   = wv >> 1, wn = wv & 1;    // wave quadrant in 64x64 tile
  const int lr   = tid >> 3;                // staging row 0..31
  const int lc   = tid & 7;                 // staging 8-elem chunk
  const int cb   = lane >> 4;
  const int fr   = lane & 15;

  // per-thread W source bases: rows r0+lr and r0+32+lr, gate-interleaved
  const int ra = r0 + lr, rb = r0 + 32 + lr;
  const float* wih0 = Wih + (size_t)((ra & 3)*1024 + (ra >> 2))*256  + lc*8;
  const float* whh0 = Whh + (size_t)((ra & 3)*1024 + (ra >> 2))*1024 + lc*8;
  const float* wih1 = Wih + (size_t)((rb & 3)*1024 + (rb >> 2))*256  + lc*8;
  const float* whh1 = Whh + (size_t)((rb & 3)*1024 + (rb >> 2))*1024 + lc*8;

  f32x4 acc[2][2] = {};

  for (int kc = 0; kc < 1280; kc += 64){
    bfx8 wh0, wl0, wh1, wl1, ah0, ah1, al0, al1;
    if (kc < 256){
      cvt8s(wih0 + kc, wh0, wl0);
      cvt8s(wih1 + kc, wh1, wl1);
      if (ENC){
        cvt8s(xsl + (size_t)(b0 + lr)      * 65536 + kc + lc*8, ah0, al0);
        cvt8s(xsl + (size_t)(b0 + 32 + lr) * 65536 + kc + lc*8, ah1, al1);
      } else {
        const size_t ao = (size_t)(b0 + lr)*256 + kc + lc*8;
        ah0 = *(const bfx8*)(iph + ao);
        ah1 = *(const bfx8*)(iph + ao + 32*256);
        al0 = *(const bfx8*)(ipl + ao);
        al1 = *(const bfx8*)(ipl + ao + 32*256);
      }
    } else {
      cvt8s(whh0 + (kc - 256), wh0, wl0);
      cvt8s(whh1 + (kc - 256), wh1, wl1);
      const size_t ao = (size_t)(b0 + lr)*2048 + (kc - 256) + lc*8;
      ah0 = *(const bfx8*)(hh + ao);
      ah1 = *(const bfx8*)(hh + ao + 32*2048);
      al0 = *(const bfx8*)(hl + ao);
      al1 = *(const bfx8*)(hl + ao + 32*2048);
    }
    __syncthreads();                         // prior iteration's LDS reads done
    *(bfx8*)&sWh[lr     ][lc*8] = wh0;
    *(bfx8*)&sWh[lr + 32][lc*8] = wh1;
    *(bfx8*)&sWl[lr     ][lc*8] = wl0;
    *(bfx8*)&sWl[lr + 32][lc*8] = wl1;
    *(bfx8*)&sAh[lr     ][lc*8] = ah0;
    *(bfx8*)&sAh[lr + 32][lc*8] = ah1;
    *(bfx8*)&sAl[lr     ][lc*8] = al0;
    *(bfx8*)&sAl[lr + 32][lc*8] = al1;
    __syncthreads();                         // tile visible
#pragma unroll
    for (int ks = 0; ks < 2; ++ks){
      const int g8 = ks*4 + cb;
      bfx8 awh0 = *(const bfx8*)&sWh[wm*32      + fr][g8*8];
      bfx8 awh1 = *(const bfx8*)&sWh[wm*32 + 16 + fr][g8*8];
      bfx8 awl0 = *(const bfx8*)&sWl[wm*32      + fr][g8*8];
      bfx8 awl1 = *(const bfx8*)&sWl[wm*32 + 16 + fr][g8*8];
      bfx8 bh0  = *(const bfx8*)&sAh[wn*32      + fr][g8*8];
      bfx8 bh1  = *(const bfx8*)&sAh[wn*32 + 16 + fr][g8*8];
      bfx8 bl0  = *(const bfx8*)&sAl[wn*32      + fr][g8*8];
      bfx8 bl1  = *(const bfx8*)&sAl[wn*32 + 16 + fr][g8*8];
      // 3-term split product per (m,nb) tile
      acc[0][0] = MFMA(awh0, bh0, acc[0][0]);
      acc[0][0] = MFMA(awh0, bl0, acc[0][0]);
      acc[0][0] = MFMA(awl0, bh0, acc[0][0]);
      acc[0][1] = MFMA(awh0, bh1, acc[0][1]);
      acc[0][1] = MFMA(awh0, bl1, acc[0][1]);
      acc[0][1] = MFMA(awl0, bh1, acc[0][1]);
      acc[1][0] = MFMA(awh1, bh0, acc[1][0]);
      acc[1][0] = MFMA(awh1, bl0, acc[1][0]);
      acc[1][0] = MFMA(awl1, bh0, acc[1][0]);
      acc[1][1] = MFMA(awh1, bh1, acc[1][1]);
      acc[1][1] = MFMA(awh1, bl1, acc[1][1]);
      acc[1][1] = MFMA(awl1, bh1, acc[1][1]);
    }
  }

  // epilogue: lane's 4 acc regs of tile (m,nb) are gates {i,f,g,o} of (n,b)
#pragma unroll
  for (int m = 0; m < 2; ++m){
    const int n = n0 + wm*8 + m*4 + cb;      // neuron (within this dir)
    const float bi = bias[n];
    const float bf = bias[1024 + n];
    const float bg = bias[2048 + n];
    const float bo = bias[3072 + n];
#pragma unroll
    for (int nb = 0; nb < 2; ++nb){
      const int b = b0 + wn*32 + nb*16 + fr;
      float gi = acc[m][nb][0] + bi;
      float gf = acc[m][nb][1] + bf;
      float gg = acc[m][nb][2] + bg;
      float go = acc[m][nb][3] + bo;
      float c_old = Cst[n*128 + b];
      float c_new = sigm(gf)*c_old + sigm(gi)*tanh_(gg);
      float h_new = sigm(go)*tanh_(c_new);
      Cst[n*128 + b] = c_new;
      unsigned short hi = f2bf(h_new);
      outh[(size_t)b*2048 + n] = hi;
      outl[(size_t)b*2048 + n] = f2bf(h_new - bf2f(hi));
    }
  }
}

// ---------------------------------------------------------------------------
// Decoder MLP: out[b][d] = hcat[b][:] @ mlp_W[d][:] + mlp_b[d], 3-term split.
// 32 WGs, tile 32d x 32b, K=2048. mlp_W staged directly from f32.
// ---------------------------------------------------------------------------
__device__ __forceinline__ void mlp_step(
    const ushort_t* __restrict__ hch,  // [128][2048] hi
    const ushort_t* __restrict__ hcl,  // [128][2048] lo
    const float*    __restrict__ mW,   // [256][2048] f32
    const float*    __restrict__ mb,   // [256] f32
    float*          __restrict__ dout, // d_out [B][T][D]
    ushort_t*       __restrict__ inph, // [128][256] next input hi
    ushort_t*       __restrict__ inpl, // lo
    int d0, int b0, int t,
    ushort_t (*sWh)[72], ushort_t (*sWl)[72],
    ushort_t (*sAh)[72], ushort_t (*sAl)[72])
{
  const int tid  = threadIdx.x;
  const int lane = tid & 63;
  const int wv   = tid >> 6;
  const int wm   = wv >> 1, wn = wv & 1;
  const int lr   = tid >> 3;
  const int lc   = tid & 7;
  const int cb   = lane >> 4;
  const int fr   = lane & 15;

  const float* wsrc = mW + (size_t)(d0 + lr)*2048 + lc*8;
  const ushort_t* ah = hch + (size_t)(b0 + lr)*2048 + lc*8;
  const ushort_t* al = hcl + (size_t)(b0 + lr)*2048 + lc*8;

  f32x4 acc = {};

  for (int kc = 0; kc < 2048; kc += 64){
    bfx8 wh, wl;
    cvt8s(wsrc + kc, wh, wl);
    bfx8 vh = *(const bfx8*)(ah + kc);
    bfx8 vl = *(const bfx8*)(al + kc);
    __syncthreads();
    *(bfx8*)&sWh[lr][lc*8] = wh;
    *(bfx8*)&sWl[lr][lc*8] = wl;
    *(bfx8*)&sAh[lr][lc*8] = vh;
    *(bfx8*)&sAl[lr][lc*8] = vl;
    __syncthreads();
#pragma unroll
    for (int ks = 0; ks < 2; ++ks){
      const int g8 = ks*4 + cb;
      bfx8 a_h = *(const bfx8*)&sWh[wm*16 + fr][g8*8];
      bfx8 a_l = *(const bfx8*)&sWl[wm*16 + fr][g8*8];
      bfx8 b_h = *(const bfx8*)&sAh[wn*16 + fr][g8*8];
      bfx8 b_l = *(const bfx8*)&sAl[wn*16 + fr][g8*8];
      acc = MFMA(a_h, b_h, acc);
      acc = MFMA(a_h, b_l, acc);
      acc = MFMA(a_l, b_h, acc);
    }
  }

  const int dr = d0 + wm*16 + cb*4;          // 4 consecutive d
  const int b  = b0 + wn*16 + fr;
  const f32x4 mb4 = *(const f32x4*)&mb[dr];
  f32x4 o = acc + mb4;
  *(f32x4*)&dout[((size_t)b*128 + t)*256 + dr] = o;  // d_out[b][t][dr..dr+3]
  u16x4 hv, lv;
#pragma unroll
  for (int j = 0; j < 4; ++j){
    hv[j] = f2bf(o[j]);
    lv[j] = f2bf(o[j] - bf2f(hv[j]));
  }
  *(u16x4*)&inph[(size_t)b*256 + dr] = hv;
  *(u16x4*)&inpl[(size_t)b*256 + dr] = lv;
}

// ---------------------------------------------------------------------------
// WG -> (dir, rowgroup, b-half); b-halves 8 apart => same XCD (round-robin).
// ---------------------------------------------------------------------------
__device__ __forceinline__ void wg_decode(int wg, int& dir, int& r0, int& n0, int& b0){
  const int half = (wg >> 3) & 1;
  const int rgd  = (wg & 7) | ((wg >> 4) << 3);        // 0..127
  dir = rgd >> 6;
  const int rg = rgd & 63;
  r0 = rg * 64; n0 = rg * 16; b0 = half * 64;
}

__global__ void __launch_bounds__(256) rnn_enc_kernel(
    const float* __restrict__ Wih_f, const float* __restrict__ Whh_f,
    const float* __restrict__ b_f,
    const float* __restrict__ Wih_b, const float* __restrict__ Whh_b,
    const float* __restrict__ b_b,
    const float* __restrict__ x,
    ushort_t* __restrict__ Hh, ushort_t* __restrict__ Hl,
    float* __restrict__ C, unsigned* cnt)
{
  __shared__ __align__(16) ushort_t sWh[64][72];
  __shared__ __align__(16) ushort_t sWl[64][72];
  __shared__ __align__(16) ushort_t sAh[64][72];
  __shared__ __align__(16) ushort_t sAl[64][72];
  int dir, r0, n0, b0;
  wg_decode(blockIdx.x, dir, r0, n0, b0);
  const float* Wih = dir ? Wih_b : Wih_f;
  const float* Whh = dir ? Whh_b : Whh_f;
  const float* bia = dir ? b_b   : b_f;
  float* Cst = C + (size_t)dir*1024*128;
  unsigned gen = 0;
  for (int t = 0; t < 256; ++t){
    const int tt = dir ? (255 - t) : t;
    const int rp = t & 1;
    cell_step<1>(Wih, Whh, bia,
                 x + (size_t)tt*256, nullptr, nullptr,
                 Hh + (size_t)rp     *262144 + dir*1024,
                 Hl + (size_t)rp     *262144 + dir*1024,
                 Hh + (size_t)(rp^1) *262144 + dir*1024,
                 Hl + (size_t)(rp^1) *262144 + dir*1024,
                 Cst, r0, n0, b0, sWh, sWl, sAh, sAl);
    ++gen;
    grid_barrier(cnt, gen * NWG);
  }
}

__global__ void __launch_bounds__(256) rnn_dec_kernel(
    const float* __restrict__ Wih_f, const float* __restrict__ Whh_f,
    const float* __restrict__ b_f,
    const float* __restrict__ Wih_b, const float* __restrict__ Whh_b,
    const float* __restrict__ b_b,
    const float* __restrict__ mW, const float* __restrict__ mb,
    ushort_t* __restrict__ Hh, ushort_t* __restrict__ Hl,
    float* __restrict__ C,
    ushort_t* __restrict__ inph, ushort_t* __restrict__ inpl,
    float* __restrict__ dout, unsigned* cnt)
{
  __shared__ __align__(16) ushort_t sWh[64][72];
  __shared__ __align__(16) ushort_t sWl[64][72];
  __shared__ __align__(16) ushort_t sAh[64][72];
  __shared__ __align__(16) ushort_t sAl[64][72];
  const int wg = blockIdx.x;
  int dir, r0, n0, b0;
  wg_decode(wg, dir, r0, n0, b0);
  const float* Wih = dir ? Wih_b : Wih_f;
  const float* Whh = dir ? Whh_b : Whh_f;
  const float* bia = dir ? b_b   : b_f;
  float* Cst = C + (size_t)dir*1024*128;
  unsigned gen = 0;
  for (int t = 0; t < 128; ++t){
    const int rp = t & 1;
    cell_step<0>(Wih, Whh, bia,
                 nullptr, inph, inpl,
                 Hh + (size_t)rp     *262144 + dir*1024,
                 Hl + (size_t)rp     *262144 + dir*1024,
                 Hh + (size_t)(rp^1) *262144 + dir*1024,
                 Hl + (size_t)(rp^1) *262144 + dir*1024,
                 Cst, r0, n0, b0, sWh, sWl, sAh, sAl);
    ++gen;
    grid_barrier(cnt, gen * NWG);
    if (wg < 32){
      mlp_step(Hh + (size_t)(rp^1)*262144, Hl + (size_t)(rp^1)*262144,
               mW, mb, dout, inph, inpl,
               (wg & 7)*32, (wg >> 3)*32, t, sWh, sWl, sAh, sAl);
    }
    ++gen;
    grid_barrier(cnt, gen * NWG);
  }
}

// ---------------------------------------------------------------------------
// Prep: zero state, build decoder's initial input planes from x[:, S-1, :]
// ---------------------------------------------------------------------------
__global__ void k_init(ushort_t* Hh, ushort_t* Hl, float* C,
                       ushort_t* inph, ushort_t* inpl,
                       const float* x, unsigned* cnt)
{
  const size_t N = 524288;  // 2 parity buffers * 128 * 2048
  for (size_t i = (size_t)blockIdx.x*blockDim.x + threadIdx.x; i < N;
       i += (size_t)gridDim.x*blockDim.x){
    Hh[i] = 0; Hl[i] = 0;
    if (i < 262144) C[i] = 0.f;
    if (i < 32768){
      int b = (int)(i >> 8), d = (int)(i & 255);
      float v = x[((size_t)b*256 + 255)*256 + d];        // x[:, 255, :]
      unsigned short hi = f2bf(v);
      inph[i] = hi;
      inpl[i] = f2bf(v - bf2f(hi));
    }
    if (i < 64) cnt[i] = 0;
  }
}

// ---------------------------------------------------------------------------
extern "C" void kernel_launch(void* const* d_in, const int* in_sizes, int n_in,
                              void* d_out, int out_size, void* d_ws, size_t ws_size,
                              hipStream_t stream)
{
  (void)in_sizes; (void)n_in; (void)out_size; (void)ws_size;
  const float* x      = (const float*)d_in[0];
  // d_in[1] = x_target (unused by reference)
  const float* eWih_f = (const float*)d_in[2];
  const float* eWhh_f = (const float*)d_in[3];
  const float* eb_f   = (const float*)d_in[4];
  const float* eWih_b = (const float*)d_in[5];
  const float* eWhh_b = (const float*)d_in[6];
  const float* eb_b   = (const float*)d_in[7];
  const float* dWih_f = (const float*)d_in[8];
  const float* dWhh_f = (const float*)d_in[9];
  const float* db_f   = (const float*)d_in[10];
  const float* dWih_b = (const float*)d_in[11];
  const float* dWhh_b = (const float*)d_in[12];
  const float* db_b   = (const float*)d_in[13];
  const float* mW     = (const float*)d_in[14];
  const float* mb     = (const float*)d_in[15];

  // minimal workspace: ~3.3 MB total
  char* p = (char*)d_ws;
  size_t off = 0;
  unsigned* cnt  = (unsigned*)(p + off);  off += 256;
  ushort_t* Hh   = (ushort_t*)(p + off);  off += 1048576;  // 2*128*2048 bf16
  ushort_t* Hl   = (ushort_t*)(p + off);  off += 1048576;
  float*    C    = (float*)(p + off);     off += 1048576;  // 2*1024*128 f32
  ushort_t* inph = (ushort_t*)(p + off);  off += 65536;    // 128*256 bf16
  ushort_t* inpl = (ushort_t*)(p + off);  off += 65536;

  k_init<<<512, 256, 0, stream>>>(Hh, Hl, C, inph, inpl, x, cnt);

  rnn_enc_kernel<<<NWG, 256, 0, stream>>>(eWih_f, eWhh_f, eb_f,
                                          eWih_b, eWhh_b, eb_b,
                                          x, Hh, Hl, C, cnt);
  rnn_dec_kernel<<<NWG, 256, 0, stream>>>(dWih_f, dWhh_f, db_f,
                                          dWih_b, dWhh_b, db_b,
                                          mW, mb, Hh, Hl, C,
                                          inph, inpl, (float*)d_out, cnt + 32);
}

// Round 5
// 27526.331 us; speedup vs baseline: 1.2097x; 1.2097x over previous
//
#include <hip/hip_runtime.h>
#include <stdint.h>

// ---------------------------------------------------------------------------
// SimpleRNN: bidirectional LSTM encoder (S=256) + autoregressive decoder (T=128)
// B=128, D=256, H=1024. Persistent kernels, hierarchical grid barriers.
// 3-term split-bf16 MFMA (Wh*Ah + Wh*Al + Wl*Ah), f32 accum/gates.
// R5: hierarchical per-dir barriers, pipelined dbuf K-loop (1 sync/iter),
// swizzled [64][64] LDS (conflict-free), materialized Whh/mlp bf16 planes.
// ---------------------------------------------------------------------------

typedef __attribute__((ext_vector_type(8))) short bfx8;
typedef __attribute__((ext_vector_type(4))) float f32x4;
typedef __attribute__((ext_vector_type(4))) unsigned short u16x4;
typedef unsigned short ushort_t;

#define NWG 256

__device__ __forceinline__ unsigned short f2bf(float f){
  unsigned u = __float_as_uint(f);
  u += 0x7FFFu + ((u >> 16) & 1u);          // round-to-nearest-even
  return (unsigned short)(u >> 16);
}
__device__ __forceinline__ float bf2f(unsigned short h){
  return __uint_as_float(((unsigned)h) << 16);
}
__device__ __forceinline__ float sigm(float x){ return 1.f/(1.f + __expf(-x)); }
__device__ __forceinline__ float tanh_(float x){ return 1.f - 2.f/(__expf(2.f*x) + 1.f); }

#define MFMA(a,b,c) __builtin_amdgcn_mfma_f32_16x16x32_bf16((a),(b),(c),0,0,0)

// Hierarchical barrier: 8 padded slot counters (slot = wg&7) + global stage.
// Monotone generation counters; loc slot gets `perslot` arrivals per gen,
// glob gets 8 per gen.
__device__ __forceinline__ void hbar(unsigned* loc, unsigned* glob,
                                     int slot, unsigned gen, unsigned perslot){
  __syncthreads();                       // all waves' mem ops drained
  if (threadIdx.x == 0){
    __threadfence();                     // release (agent scope)
    unsigned a = atomicAdd(loc + slot*16, 1u);
    if (a == gen*perslot - 1u)
      atomicAdd(glob, 1u);               // last arriver of this slot
    while (__hip_atomic_load(glob, __ATOMIC_ACQUIRE, __HIP_MEMORY_SCOPE_AGENT) < gen*8u)
      __builtin_amdgcn_s_sleep(2);
    __threadfence();                     // acquire
  }
  __syncthreads();
}

// 8 consecutive f32 -> split hi+lo bf16 (RNE both)
__device__ __forceinline__ void cvt8s(const float* p, bfx8& hi, bfx8& lo){
  f32x4 a = *(const f32x4*)p;
  f32x4 b = *(const f32x4*)(p + 4);
#pragma unroll
  for (int j = 0; j < 4; ++j){
    unsigned short h0 = f2bf(a[j]);
    unsigned short h1 = f2bf(b[j]);
    hi[j]   = (short)h0; lo[j]   = (short)f2bf(a[j] - bf2f(h0));
    hi[4+j] = (short)h1; lo[4+j] = (short)f2bf(b[j] - bf2f(h1));
  }
}

struct Chunk { bfx8 wh0, wh1, wl0, wl1, ah0, ah1, al0, al1; };

// ---------------------------------------------------------------------------
// One LSTM cell step: WG owns 64 gate-interleaved W-rows' (16 neurons) x 64
// batches. g = [x|h] @ W'.T via 3-term split. D[r'][b]: lane's 4 acc regs =
// gates {i,f,g,o} of one (n,b).
// LDS: [2 bufs][64][64] ushort, pre-swizzled source column sc8 = lc^(lr&7),
// read granule g8^(fr&7). Pipelined: 1 syncthreads/iter, loads overlap MFMA.
// ---------------------------------------------------------------------------
template<int ENC>
__device__ __forceinline__ void cell_step(
    const float*    __restrict__ Wih,   // [4096][256] f32 original (this dir)
    const ushort_t* __restrict__ WhhH,  // [4096][1024] bf16 hi plane (this dir)
    const ushort_t* __restrict__ WhhL,  // lo plane
    const float*    __restrict__ bias,  // [4096] f32 (original order)
    const float*    __restrict__ xsl,   // ENC: x + tt*256 (row stride 65536)
    const ushort_t* __restrict__ iph,   // DEC: [128][256] hi
    const ushort_t* __restrict__ ipl,   // DEC: lo
    const ushort_t* __restrict__ hh,    // h hi (base + dir*1024), stride 2048
    const ushort_t* __restrict__ hl,    // h lo
    ushort_t* __restrict__ outh, ushort_t* __restrict__ outl,
    float* __restrict__ Cst,            // [1024][128] f32 (this dir)
    int r0, int n0, int b0,
    ushort_t (*sWh)[64][64], ushort_t (*sWl)[64][64],
    ushort_t (*sAh)[64][64], ushort_t (*sAl)[64][64])
{
  const int tid  = threadIdx.x;
  const int lane = tid & 63;
  const int wv   = tid >> 6;
  const int wm   = wv >> 1, wn = wv & 1;   // wave quadrant in 64x64 tile
  const int lr   = tid >> 3;               // staging row 0..31
  const int lc   = tid & 7;                // staging chunk (physical)
  const int cb   = lane >> 4;
  const int fr   = lane & 15;
  const int sc8  = lc ^ (lr & 7);          // pre-swizzled SOURCE column chunk

  // per-thread global bases (rows r0+lr, r0+32+lr)
  const int ra = r0 + lr, rb = ra + 32;
  const float* wih0 = Wih + (size_t)((ra & 3)*1024 + (ra >> 2))*256 + sc8*8;
  const float* wih1 = Wih + (size_t)((rb & 3)*1024 + (rb >> 2))*256 + sc8*8;
  const ushort_t* whhh0 = WhhH + (size_t)ra*1024 + sc8*8;
  const ushort_t* whhh1 = WhhH + (size_t)rb*1024 + sc8*8;
  const ushort_t* whhl0 = WhhL + (size_t)ra*1024 + sc8*8;
  const ushort_t* whhl1 = WhhL + (size_t)rb*1024 + sc8*8;
  const float *xs0 = nullptr, *xs1 = nullptr;
  const ushort_t *ih0 = nullptr, *ih1 = nullptr, *il0 = nullptr, *il1 = nullptr;
  if (ENC){
    xs0 = xsl + (size_t)(b0 + lr)*65536 + sc8*8;
    xs1 = xs0 + (size_t)32*65536;
  } else {
    ih0 = iph + (size_t)(b0 + lr)*256 + sc8*8;  ih1 = ih0 + 32*256;
    il0 = ipl + (size_t)(b0 + lr)*256 + sc8*8;  il1 = il0 + 32*256;
  }
  const ushort_t* h0 = hh + (size_t)(b0 + lr)*2048 + sc8*8;
  const ushort_t* h1 = h0 + 32*2048;
  const ushort_t* l0 = hl + (size_t)(b0 + lr)*2048 + sc8*8;
  const ushort_t* l1 = l0 + 32*2048;

  auto LOADC = [&](int kc, Chunk& c){
    if (kc < 256){
      cvt8s(wih0 + kc, c.wh0, c.wl0);
      cvt8s(wih1 + kc, c.wh1, c.wl1);
      if (ENC){
        cvt8s(xs0 + kc, c.ah0, c.al0);
        cvt8s(xs1 + kc, c.ah1, c.al1);
      } else {
        c.ah0 = *(const bfx8*)(ih0 + kc);
        c.ah1 = *(const bfx8*)(ih1 + kc);
        c.al0 = *(const bfx8*)(il0 + kc);
        c.al1 = *(const bfx8*)(il1 + kc);
      }
    } else {
      const int k2 = kc - 256;
      c.wh0 = *(const bfx8*)(whhh0 + k2);
      c.wh1 = *(const bfx8*)(whhh1 + k2);
      c.wl0 = *(const bfx8*)(whhl0 + k2);
      c.wl1 = *(const bfx8*)(whhl1 + k2);
      c.ah0 = *(const bfx8*)(h0 + k2);
      c.ah1 = *(const bfx8*)(h1 + k2);
      c.al0 = *(const bfx8*)(l0 + k2);
      c.al1 = *(const bfx8*)(l1 + k2);
    }
  };

  f32x4 acc[2][2] = {};
  Chunk cur, nxt;
  LOADC(0, cur);
  int p = 0;
  const int rwa0 = wm*32 + fr, rwa1 = rwa0 + 16;
  const int rwb0 = wn*32 + fr, rwb1 = rwb0 + 16;
  const int sx = fr & 7;

  for (int kc = 0; kc < 1280; kc += 64, p ^= 1){
    // stage current chunk (wave-linear, conflict-free)
    *(bfx8*)&sWh[p][lr   ][lc*8] = cur.wh0;
    *(bfx8*)&sWh[p][lr+32][lc*8] = cur.wh1;
    *(bfx8*)&sWl[p][lr   ][lc*8] = cur.wl0;
    *(bfx8*)&sWl[p][lr+32][lc*8] = cur.wl1;
    *(bfx8*)&sAh[p][lr   ][lc*8] = cur.ah0;
    *(bfx8*)&sAh[p][lr+32][lc*8] = cur.ah1;
    *(bfx8*)&sAl[p][lr   ][lc*8] = cur.al0;
    *(bfx8*)&sAl[p][lr+32][lc*8] = cur.al1;
    __syncthreads();                       // tile visible; prior reads drained
    if (kc < 1216) LOADC(kc + 64, nxt);    // issue loads — overlap with MFMA
#pragma unroll
    for (int ks = 0; ks < 2; ++ks){
      const int ga = ((ks*4 + cb) ^ sx)*8; // swizzled read granule
      bfx8 awh0 = *(const bfx8*)&sWh[p][rwa0][ga];
      bfx8 awh1 = *(const bfx8*)&sWh[p][rwa1][ga];
      bfx8 awl0 = *(const bfx8*)&sWl[p][rwa0][ga];
      bfx8 awl1 = *(const bfx8*)&sWl[p][rwa1][ga];
      bfx8 bh0  = *(const bfx8*)&sAh[p][rwb0][ga];
      bfx8 bh1  = *(const bfx8*)&sAh[p][rwb1][ga];
      bfx8 bl0  = *(const bfx8*)&sAl[p][rwb0][ga];
      bfx8 bl1  = *(const bfx8*)&sAl[p][rwb1][ga];
      acc[0][0] = MFMA(awh0, bh0, acc[0][0]);
      acc[0][0] = MFMA(awh0, bl0, acc[0][0]);
      acc[0][0] = MFMA(awl0, bh0, acc[0][0]);
      acc[0][1] = MFMA(awh0, bh1, acc[0][1]);
      acc[0][1] = MFMA(awh0, bl1, acc[0][1]);
      acc[0][1] = MFMA(awl0, bh1, acc[0][1]);
      acc[1][0] = MFMA(awh1, bh0, acc[1][0]);
      acc[1][0] = MFMA(awh1, bl0, acc[1][0]);
      acc[1][0] = MFMA(awl1, bh0, acc[1][0]);
      acc[1][1] = MFMA(awh1, bh1, acc[1][1]);
      acc[1][1] = MFMA(awh1, bl1, acc[1][1]);
      acc[1][1] = MFMA(awl1, bh1, acc[1][1]);
    }
    cur = nxt;
  }

  // epilogue: lane's 4 acc regs of tile (m,nb) = gates {i,f,g,o} of (n,b)
#pragma unroll
  for (int m = 0; m < 2; ++m){
    const int n = n0 + wm*8 + m*4 + cb;
    const float bi = bias[n];
    const float bf = bias[1024 + n];
    const float bg = bias[2048 + n];
    const float bo = bias[3072 + n];
#pragma unroll
    for (int nb = 0; nb < 2; ++nb){
      const int b = b0 + wn*32 + nb*16 + fr;
      float gi = acc[m][nb][0] + bi;
      float gf = acc[m][nb][1] + bf;
      float gg = acc[m][nb][2] + bg;
      float go = acc[m][nb][3] + bo;
      float c_old = Cst[n*128 + b];
      float c_new = sigm(gf)*c_old + sigm(gi)*tanh_(gg);
      float h_new = sigm(go)*tanh_(c_new);
      Cst[n*128 + b] = c_new;
      unsigned short hi = f2bf(h_new);
      outh[(size_t)b*2048 + n] = hi;
      outl[(size_t)b*2048 + n] = f2bf(h_new - bf2f(hi));
    }
  }
}

// ---------------------------------------------------------------------------
// Decoder MLP: out[b][d] = hcat[b][:] @ mlp_W[d][:] + mlp_b[d], 3-term split.
// 32 WGs, tile 32d x 32b, K=2048, pipelined dbuf.
// ---------------------------------------------------------------------------
__device__ __forceinline__ void mlp_step(
    const ushort_t* __restrict__ hch,  // [128][2048] hi
    const ushort_t* __restrict__ hcl,  // lo
    const ushort_t* __restrict__ mWh,  // [256][2048] bf16 hi
    const ushort_t* __restrict__ mWl,  // lo
    const float*    __restrict__ mb,   // [256] f32
    float*          __restrict__ dout,
    ushort_t* __restrict__ inph, ushort_t* __restrict__ inpl,
    int d0, int b0, int t,
    ushort_t (*sWh)[64][64], ushort_t (*sWl)[64][64],
    ushort_t (*sAh)[64][64], ushort_t (*sAl)[64][64])
{
  const int tid  = threadIdx.x;
  const int lane = tid & 63;
  const int wv   = tid >> 6;
  const int wm   = wv >> 1, wn = wv & 1;
  const int lr   = tid >> 3;               // 0..31
  const int lc   = tid & 7;
  const int cb   = lane >> 4;
  const int fr   = lane & 15;
  const int sc8  = lc ^ (lr & 7);

  const ushort_t* wh = mWh + (size_t)(d0 + lr)*2048 + sc8*8;
  const ushort_t* wl = mWl + (size_t)(d0 + lr)*2048 + sc8*8;
  const ushort_t* ah = hch + (size_t)(b0 + lr)*2048 + sc8*8;
  const ushort_t* al = hcl + (size_t)(b0 + lr)*2048 + sc8*8;

  f32x4 acc = {};
  bfx8 cwh = *(const bfx8*)wh, cwl = *(const bfx8*)wl;
  bfx8 cah = *(const bfx8*)ah, cal = *(const bfx8*)al;
  bfx8 nwh, nwl, nah, nal;
  int p = 0;
  const int rwa = wm*16 + fr, rwb = wn*16 + fr;
  const int sx = fr & 7;

  for (int kc = 0; kc < 2048; kc += 64, p ^= 1){
    *(bfx8*)&sWh[p][lr][lc*8] = cwh;
    *(bfx8*)&sWl[p][lr][lc*8] = cwl;
    *(bfx8*)&sAh[p][lr][lc*8] = cah;
    *(bfx8*)&sAl[p][lr][lc*8] = cal;
    __syncthreads();
    if (kc < 1984){
      nwh = *(const bfx8*)(wh + kc + 64);
      nwl = *(const bfx8*)(wl + kc + 64);
      nah = *(const bfx8*)(ah + kc + 64);
      nal = *(const bfx8*)(al + kc + 64);
    }
#pragma unroll
    for (int ks = 0; ks < 2; ++ks){
      const int ga = ((ks*4 + cb) ^ sx)*8;
      bfx8 a_h = *(const bfx8*)&sWh[p][rwa][ga];
      bfx8 a_l = *(const bfx8*)&sWl[p][rwa][ga];
      bfx8 b_h = *(const bfx8*)&sAh[p][rwb][ga];
      bfx8 b_l = *(const bfx8*)&sAl[p][rwb][ga];
      acc = MFMA(a_h, b_h, acc);
      acc = MFMA(a_h, b_l, acc);
      acc = MFMA(a_l, b_h, acc);
    }
    cwh = nwh; cwl = nwl; cah = nah; cal = nal;
  }

  const int dr = d0 + wm*16 + cb*4;
  const int b  = b0 + wn*16 + fr;
  const f32x4 mb4 = *(const f32x4*)&mb[dr];
  f32x4 o = acc + mb4;
  *(f32x4*)&dout[((size_t)b*128 + t)*256 + dr] = o;
  u16x4 hv, lv;
#pragma unroll
  for (int j = 0; j < 4; ++j){
    hv[j] = f2bf(o[j]);
    lv[j] = f2bf(o[j] - bf2f(hv[j]));
  }
  *(u16x4*)&inph[(size_t)b*256 + dr] = hv;
  *(u16x4*)&inpl[(size_t)b*256 + dr] = lv;
}

// ---------------------------------------------------------------------------
// WG -> (dir, rowgroup, b-half); b-halves 8 apart => same XCD (round-robin).
// dir0 = wg<128, dir1 = wg>=128.
// ---------------------------------------------------------------------------
__device__ __forceinline__ void wg_decode(int wg, int& dir, int& r0, int& n0, int& b0){
  const int half = (wg >> 3) & 1;
  const int rgd  = (wg & 7) | ((wg >> 4) << 3);        // 0..127
  dir = rgd >> 6;
  const int rg = rgd & 63;
  r0 = rg * 64; n0 = rg * 16; b0 = half * 64;
}

__global__ void __launch_bounds__(256) rnn_enc_kernel(
    const float* __restrict__ Wih_f, const float* __restrict__ b_f,
    const float* __restrict__ Wih_b, const float* __restrict__ b_b,
    const ushort_t* __restrict__ WhhH, const ushort_t* __restrict__ WhhL,
    const float* __restrict__ x,
    ushort_t* __restrict__ Hh, ushort_t* __restrict__ Hl,
    float* __restrict__ C, unsigned* cnt)
{
  __shared__ __align__(16) ushort_t sWh[2][64][64];
  __shared__ __align__(16) ushort_t sWl[2][64][64];
  __shared__ __align__(16) ushort_t sAh[2][64][64];
  __shared__ __align__(16) ushort_t sAl[2][64][64];
  int dir, r0, n0, b0;
  wg_decode(blockIdx.x, dir, r0, n0, b0);
  const float* Wih = dir ? Wih_b : Wih_f;
  const float* bia = dir ? b_b   : b_f;
  const ushort_t* WhH = WhhH + (size_t)dir*4096*1024;
  const ushort_t* WhL = WhhL + (size_t)dir*4096*1024;
  float* Cst = C + (size_t)dir*1024*128;
  unsigned* loc  = cnt + dir*256;            // per-direction barrier
  unsigned* glob = loc + 144;
  const int slot = blockIdx.x & 7;
  unsigned gen = 0;
  for (int t = 0; t < 256; ++t){
    const int tt = dir ? (255 - t) : t;
    const int rp = t & 1;
    cell_step<1>(Wih, WhH, WhL, bia,
                 x + (size_t)tt*256, nullptr, nullptr,
                 Hh + (size_t)rp     *262144 + dir*1024,
                 Hl + (size_t)rp     *262144 + dir*1024,
                 Hh + (size_t)(rp^1) *262144 + dir*1024,
                 Hl + (size_t)(rp^1) *262144 + dir*1024,
                 Cst, r0, n0, b0, sWh, sWl, sAh, sAl);
    ++gen;
    hbar(loc, glob, slot, gen, 16);          // 128 WGs per dir, 16 per slot
  }
}

__global__ void __launch_bounds__(256) rnn_dec_kernel(
    const float* __restrict__ Wih_f, const float* __restrict__ b_f,
    const float* __restrict__ Wih_b, const float* __restrict__ b_b,
    const ushort_t* __restrict__ WhhH, const ushort_t* __restrict__ WhhL,
    const ushort_t* __restrict__ mWh, const ushort_t* __restrict__ mWl,
    const float* __restrict__ mb,
    ushort_t* __restrict__ Hh, ushort_t* __restrict__ Hl,
    float* __restrict__ C,
    ushort_t* __restrict__ inph, ushort_t* __restrict__ inpl,
    float* __restrict__ dout, unsigned* cnt)
{
  __shared__ __align__(16) ushort_t sWh[2][64][64];
  __shared__ __align__(16) ushort_t sWl[2][64][64];
  __shared__ __align__(16) ushort_t sAh[2][64][64];
  __shared__ __align__(16) ushort_t sAl[2][64][64];
  const int wg = blockIdx.x;
  int dir, r0, n0, b0;
  wg_decode(wg, dir, r0, n0, b0);
  const float* Wih = dir ? Wih_b : Wih_f;
  const float* bia = dir ? b_b   : b_f;
  const ushort_t* WhH = WhhH + (size_t)dir*4096*1024;
  const ushort_t* WhL = WhhL + (size_t)dir*4096*1024;
  float* Cst = C + (size_t)dir*1024*128;
  unsigned* loc  = cnt;                      // full 256-WG barrier
  unsigned* glob = cnt + 144;
  const int slot = wg & 7;
  unsigned gen = 0;
  for (int t = 0; t < 128; ++t){
    const int rp = t & 1;
    cell_step<0>(Wih, WhH, WhL, bia,
                 nullptr, inph, inpl,
                 Hh + (size_t)rp     *262144 + dir*1024,
                 Hl + (size_t)rp     *262144 + dir*1024,
                 Hh + (size_t)(rp^1) *262144 + dir*1024,
                 Hl + (size_t)(rp^1) *262144 + dir*1024,
                 Cst, r0, n0, b0, sWh, sWl, sAh, sAl);
    ++gen;
    hbar(loc, glob, slot, gen, 32);
    if (wg < 32){
      mlp_step(Hh + (size_t)(rp^1)*262144, Hl + (size_t)(rp^1)*262144,
               mWh, mWl, mb, dout, inph, inpl,
               (wg & 7)*32, (wg >> 3)*32, t, sWh, sWl, sAh, sAl);
    }
    ++gen;
    hbar(loc, glob, slot, gen, 32);
  }
}

// ---------------------------------------------------------------------------
// Prep kernels
// ---------------------------------------------------------------------------
// Gate-interleaved Whh hi/lo planes: P[(dir*4096 + 4n+q)*1024 + k] from
// Whh_dir[q*1024+n][k].
__global__ void k_wplanes(ushort_t* Hp, ushort_t* Lp,
                          const float* Whh_f, const float* Whh_b)
{
  const size_t N = 2ull*4096*1024;
  for (size_t i = (size_t)blockIdx.x*blockDim.x + threadIdx.x; i < N;
       i += (size_t)gridDim.x*blockDim.x){
    int dir = (int)(i >> 22);
    int r   = (int)((i >> 10) & 4095);
    int k   = (int)(i & 1023);
    int n = r >> 2, q = r & 3;
    const float* W = dir ? Whh_b : Whh_f;
    float v = W[(size_t)(q*1024 + n)*1024 + k];
    unsigned short h = f2bf(v);
    Hp[i] = h;
    Lp[i] = f2bf(v - bf2f(h));
  }
}

__global__ void k_init(ushort_t* Hh, ushort_t* Hl, float* C,
                       ushort_t* inph, ushort_t* inpl,
                       ushort_t* mWh, ushort_t* mWl,
                       const float* x, const float* mW, unsigned* cnt)
{
  const size_t N = 524288;  // 2 parity * 128 * 2048 == 256*2048 (mlp)
  for (size_t i = (size_t)blockIdx.x*blockDim.x + threadIdx.x; i < N;
       i += (size_t)gridDim.x*blockDim.x){
    Hh[i] = 0; Hl[i] = 0;
    float wv = mW[i];
    unsigned short wh = f2bf(wv);
    mWh[i] = wh;
    mWl[i] = f2bf(wv - bf2f(wh));
    if (i < 262144) C[i] = 0.f;
    if (i < 32768){
      int b = (int)(i >> 8), d = (int)(i & 255);
      float v = x[((size_t)b*256 + 255)*256 + d];        // x[:, 255, :]
      unsigned short hi = f2bf(v);
      inph[i] = hi;
      inpl[i] = f2bf(v - bf2f(hi));
    }
    if (i < 1024) cnt[i] = 0;
  }
}

// ---------------------------------------------------------------------------
extern "C" void kernel_launch(void* const* d_in, const int* in_sizes, int n_in,
                              void* d_out, int out_size, void* d_ws, size_t ws_size,
                              hipStream_t stream)
{
  (void)in_sizes; (void)n_in; (void)out_size; (void)ws_size;
  const float* x      = (const float*)d_in[0];
  const float* eWih_f = (const float*)d_in[2];
  const float* eWhh_f = (const float*)d_in[3];
  const float* eb_f   = (const float*)d_in[4];
  const float* eWih_b = (const float*)d_in[5];
  const float* eWhh_b = (const float*)d_in[6];
  const float* eb_b   = (const float*)d_in[7];
  const float* dWih_f = (const float*)d_in[8];
  const float* dWhh_f = (const float*)d_in[9];
  const float* db_f   = (const float*)d_in[10];
  const float* dWih_b = (const float*)d_in[11];
  const float* dWhh_b = (const float*)d_in[12];
  const float* db_b   = (const float*)d_in[13];
  const float* mW     = (const float*)d_in[14];
  const float* mb     = (const float*)d_in[15];

  // workspace layout (~72.5 MB; evidence ws >= ~79 MB from R2/R3 bit-identity)
  char* p = (char*)d_ws;
  size_t off = 0;
  unsigned* cnt   = (unsigned*)(p + off);  off += 4096;
  ushort_t* WhhEh = (ushort_t*)(p + off);  off += 16777216;  // 2*4096*1024 bf16
  ushort_t* WhhEl = (ushort_t*)(p + off);  off += 16777216;
  ushort_t* WhhDh = (ushort_t*)(p + off);  off += 16777216;
  ushort_t* WhhDl = (ushort_t*)(p + off);  off += 16777216;
  ushort_t* mWh   = (ushort_t*)(p + off);  off += 1048576;   // 256*2048 bf16
  ushort_t* mWl   = (ushort_t*)(p + off);  off += 1048576;
  ushort_t* Hh    = (ushort_t*)(p + off);  off += 1048576;   // 2*128*2048 bf16
  ushort_t* Hl    = (ushort_t*)(p + off);  off += 1048576;
  float*    C     = (float*)(p + off);     off += 1048576;   // 2*1024*128 f32
  ushort_t* inph  = (ushort_t*)(p + off);  off += 65536;
  ushort_t* inpl  = (ushort_t*)(p + off);  off += 65536;

  k_init   <<<512, 256, 0, stream>>>(Hh, Hl, C, inph, inpl, mWh, mWl, x, mW, cnt);
  k_wplanes<<<2048, 256, 0, stream>>>(WhhEh, WhhEl, eWhh_f, eWhh_b);
  k_wplanes<<<2048, 256, 0, stream>>>(WhhDh, WhhDl, dWhh_f, dWhh_b);

  rnn_enc_kernel<<<NWG, 256, 0, stream>>>(eWih_f, eb_f, eWih_b, eb_b,
                                          WhhEh, WhhEl, x, Hh, Hl, C, cnt);
  rnn_dec_kernel<<<NWG, 256, 0, stream>>>(dWih_f, db_f, dWih_b, db_b,
                                          WhhDh, WhhDl, mWh, mWl, mb,
                                          Hh, Hl, C, inph, inpl,
                                          (float*)d_out, cnt + 512);
}

// Round 6
// 16312.372 us; speedup vs baseline: 2.0414x; 1.6875x over previous
//
#include <hip/hip_runtime.h>
#include <stdint.h>

// ---------------------------------------------------------------------------
// SimpleRNN: bidirectional LSTM encoder (S=256) + autoregressive decoder (T=128)
// B=128, D=256, H=1024. Persistent kernels, flag-based grid barriers.
// 3-term split-bf16 MFMA (Wh*Ah + Wh*Al + Wl*Ah), f32 accum/gates.
// R6: deep-pipelined K-loop (global_load_lds, depth-3 ring, counted vmcnt,
// raw s_barrier), c-state in registers, 256-WG K-split MLP (wave-private
// staging, no inner barriers), flag/scan grid barrier. 128KB dynamic LDS.
// ---------------------------------------------------------------------------

typedef __attribute__((ext_vector_type(8))) short bfx8;
typedef __attribute__((ext_vector_type(4))) float f32x4;
typedef __attribute__((ext_vector_type(4))) unsigned short u16x4;
typedef unsigned short ushort_t;

#define NWG 256
#define MFMA(a,b,c) __builtin_amdgcn_mfma_f32_16x16x32_bf16((a),(b),(c),0,0,0)
#define WAITVM(N) { asm volatile("s_waitcnt vmcnt(" #N ")" ::: "memory"); __builtin_amdgcn_sched_barrier(0); }
#define WAITLG(N) { asm volatile("s_waitcnt lgkmcnt(" #N ")" ::: "memory"); __builtin_amdgcn_sched_barrier(0); }
#define SBAR()    { __builtin_amdgcn_s_barrier(); __builtin_amdgcn_sched_barrier(0); }

__device__ __forceinline__ unsigned short f2bf(float f){
  unsigned u = __float_as_uint(f);
  u += 0x7FFFu + ((u >> 16) & 1u);          // round-to-nearest-even
  return (unsigned short)(u >> 16);
}
__device__ __forceinline__ float bf2f(unsigned short h){
  return __uint_as_float(((unsigned)h) << 16);
}
__device__ __forceinline__ float sigm(float x){ return 1.f/(1.f + __expf(-x)); }
__device__ __forceinline__ float tanh_(float x){ return 1.f - 2.f/(__expf(2.f*x) + 1.f); }

__device__ __forceinline__ void stage16(const void* g, void* l){
  __builtin_amdgcn_global_load_lds((const __attribute__((address_space(1))) void*)g,
                                   (__attribute__((address_space(3))) void*)l,
                                   16, 0, 0);
}

// two f32x4 (8 consecutive f32) -> hi/lo bf16 planes
__device__ __forceinline__ void cvt2(const f32x4& a, const f32x4& b, bfx8& hi, bfx8& lo){
#pragma unroll
  for (int j = 0; j < 4; ++j){
    unsigned short h0 = f2bf(a[j]);
    unsigned short h1 = f2bf(b[j]);
    hi[j]   = (short)h0; lo[j]   = (short)f2bf(a[j] - bf2f(h0));
    hi[4+j] = (short)h1; lo[4+j] = (short)f2bf(b[j] - bf2f(h1));
  }
}

// ---------------------------------------------------------------------------
// Flag-based grid barrier: store own flag, wave0 scans all flags (coalesced
// per-lane atomic loads), acquire fence, syncthreads.
// ---------------------------------------------------------------------------
__device__ __forceinline__ void bar(unsigned* flags, int nflags, int me, unsigned gen){
  __syncthreads();                       // drain all waves' mem ops
  if (threadIdx.x == 0){
    __threadfence();                     // release (agent): writeback
    __hip_atomic_store(&flags[me], gen, __ATOMIC_RELAXED, __HIP_MEMORY_SCOPE_AGENT);
  }
  if (threadIdx.x < 64){
    const int l = threadIdx.x;
    for (;;){
      unsigned mn = 0xFFFFFFFFu;
      for (int o = l; o < nflags; o += 64){
        unsigned v = __hip_atomic_load(&flags[o], __ATOMIC_RELAXED, __HIP_MEMORY_SCOPE_AGENT);
        mn = mn < v ? mn : v;
      }
      if (__all((int)(mn >= gen))) break;
      __builtin_amdgcn_s_sleep(4);
    }
    __threadfence();                     // acquire: invalidate caches
  }
  __syncthreads();
}

struct Frags { bfx8 awh0, awh1, awl0, awl1, bh0, bh1, bl0, bl1; };

// ---------------------------------------------------------------------------
// One LSTM cell step. WG owns 64 gate-interleaved W-rows' (16 neurons) x 64
// batches. Phase 1 (k<256, 4 chunks): register-staged (f32 cvt). Phase 2
// (k in [256,1280), 16 chunks): global_load_lds depth-3 ring, counted vmcnt.
// LDS (ushort units): P1 planes @0/4096/8192/12288; ring buf bp @16384+bp*16384.
// ---------------------------------------------------------------------------
template<int ENC>
__device__ __forceinline__ void cell_step(
    const float*    __restrict__ Wih,   // [4096][256] f32 original (this dir)
    const ushort_t* __restrict__ WhH,   // [4096][1024] bf16 hi (this dir)
    const ushort_t* __restrict__ WhL,   // lo
    const float*    __restrict__ bias,  // [4096] f32 (original order)
    const float*    __restrict__ xsl,   // ENC: x + tt*256 (row stride 65536)
    const ushort_t* __restrict__ iph,   // DEC: [128][256] hi
    const ushort_t* __restrict__ ipl,   // DEC: lo
    const ushort_t* __restrict__ hh,    // h hi (base + dir*1024), stride 2048
    const ushort_t* __restrict__ hl,    // h lo
    ushort_t* __restrict__ outh, ushort_t* __restrict__ outl,
    float (&creg)[2][2],
    int r0, int n0, int b0, ushort_t* LDS)
{
  const int tid  = threadIdx.x;
  const int lane = tid & 63;
  const int wv   = tid >> 6;
  const int wm   = wv >> 1, wn = wv & 1;
  const int lr   = tid >> 3;               // phase-1 staging row 0..31
  const int lc   = tid & 7;
  const int cb   = lane >> 4;
  const int fr   = lane & 15;
  const int sc8  = lc ^ (lr & 7);          // phase-1 pre-swizzled source chunk
  const int sx   = fr & 7;
  const int rwa0 = wm*32 + fr, rwa1 = rwa0 + 16;
  const int rwb0 = wn*32 + fr, rwb1 = rwb0 + 16;

  // ---- phase-1 source pointers (rows r0+lr, r0+32+lr; gate-interleaved) ----
  const int ra = r0 + lr, rb = ra + 32;
  const float* wih0 = Wih + (size_t)((ra & 3)*1024 + (ra >> 2))*256 + sc8*8;
  const float* wih1 = Wih + (size_t)((rb & 3)*1024 + (rb >> 2))*256 + sc8*8;
  const float *xs0 = nullptr, *xs1 = nullptr;
  const ushort_t *ih0 = nullptr, *ih1 = nullptr, *il0 = nullptr, *il1 = nullptr;
  if (ENC){
    xs0 = xsl + (size_t)(b0 + lr)*65536 + sc8*8;
    xs1 = xs0 + (size_t)32*65536;
  } else {
    ih0 = iph + (size_t)(b0 + lr)*256 + sc8*8;  ih1 = ih0 + 32*256;
    il0 = ipl + (size_t)(b0 + lr)*256 + sc8*8;  il1 = il0 + 32*256;
  }

  // ---- phase-2 staging bases: wave wv stages plane wv ----
  const ushort_t* sb; size_t sstr; int srow0;
  if      (wv == 0){ sb = WhH; sstr = 1024; srow0 = r0; }
  else if (wv == 1){ sb = WhL; sstr = 1024; srow0 = r0; }
  else if (wv == 2){ sb = hh;  sstr = 2048; srow0 = b0; }
  else             { sb = hl;  sstr = 2048; srow0 = b0; }
  const int srw = lane >> 3;
  const int sg  = (lane & 7) ^ srw;        // swizzled source granule
  const ushort_t* pj[8];
#pragma unroll
  for (int j = 0; j < 8; ++j)
    pj[j] = sb + (size_t)(srow0 + j*8 + srw)*sstr + sg*8;
  ushort_t* ldsb[3];
#pragma unroll
  for (int bp = 0; bp < 3; ++bp)
    ldsb[bp] = LDS + 16384 + bp*16384 + wv*4096;

  auto ISSUE = [&](int c, int bp){
    const int ko = (c - 4)*64;
#pragma unroll
    for (int j = 0; j < 8; ++j)
      stage16(pj[j] + ko, ldsb[bp] + j*512);
  };

  f32x4 acc[2][2] = {};
  auto rdf = [&](const ushort_t* buf, int ks, Frags& f){
    const int ga = (((ks << 2) + cb) ^ sx) << 3;
    f.awh0 = *(const bfx8*)(buf +         rwa0*64 + ga);
    f.awh1 = *(const bfx8*)(buf +         rwa1*64 + ga);
    f.awl0 = *(const bfx8*)(buf + 4096  + rwa0*64 + ga);
    f.awl1 = *(const bfx8*)(buf + 4096  + rwa1*64 + ga);
    f.bh0  = *(const bfx8*)(buf + 8192  + rwb0*64 + ga);
    f.bh1  = *(const bfx8*)(buf + 8192  + rwb1*64 + ga);
    f.bl0  = *(const bfx8*)(buf + 12288 + rwb0*64 + ga);
    f.bl1  = *(const bfx8*)(buf + 12288 + rwb1*64 + ga);
  };
  auto mm12 = [&](const Frags& f){
    acc[0][0] = MFMA(f.awh0, f.bh0, acc[0][0]);
    acc[0][0] = MFMA(f.awh0, f.bl0, acc[0][0]);
    acc[0][0] = MFMA(f.awl0, f.bh0, acc[0][0]);
    acc[0][1] = MFMA(f.awh0, f.bh1, acc[0][1]);
    acc[0][1] = MFMA(f.awh0, f.bl1, acc[0][1]);
    acc[0][1] = MFMA(f.awl0, f.bh1, acc[0][1]);
    acc[1][0] = MFMA(f.awh1, f.bh0, acc[1][0]);
    acc[1][0] = MFMA(f.awh1, f.bl0, acc[1][0]);
    acc[1][0] = MFMA(f.awl1, f.bh0, acc[1][0]);
    acc[1][1] = MFMA(f.awh1, f.bh1, acc[1][1]);
    acc[1][1] = MFMA(f.awh1, f.bl1, acc[1][1]);
    acc[1][1] = MFMA(f.awl1, f.bh1, acc[1][1]);
  };

  // ---- phase-1 raw loads / cvt ----
  f32x4 rw0a, rw0b, rw1a, rw1b, rxa0, rxb0, rxa1, rxb1;
  bfx8 cwh0, cwh1, cwl0, cwl1, cah0, cah1, cal0, cal1;
  auto LOADRAW = [&](int kc){
    rw0a = *(const f32x4*)(wih0 + kc);  rw0b = *(const f32x4*)(wih0 + kc + 4);
    rw1a = *(const f32x4*)(wih1 + kc);  rw1b = *(const f32x4*)(wih1 + kc + 4);
    if (ENC){
      rxa0 = *(const f32x4*)(xs0 + kc); rxb0 = *(const f32x4*)(xs0 + kc + 4);
      rxa1 = *(const f32x4*)(xs1 + kc); rxb1 = *(const f32x4*)(xs1 + kc + 4);
    } else {
      cah0 = *(const bfx8*)(ih0 + kc);  cah1 = *(const bfx8*)(ih1 + kc);
      cal0 = *(const bfx8*)(il0 + kc);  cal1 = *(const bfx8*)(il1 + kc);
    }
  };
  auto CVT = [&](){
    cvt2(rw0a, rw0b, cwh0, cwl0);
    cvt2(rw1a, rw1b, cwh1, cwl1);
    if (ENC){ cvt2(rxa0, rxb0, cah0, cal0); cvt2(rxa1, rxb1, cah1, cal1); }
  };

  LOADRAW(0);
  ISSUE(4, 0); ISSUE(5, 1); ISSUE(6, 2);     // phase-2 prologue (24 in flight)
  CVT();

  // ---- phase 1: chunks 0..3, register-staged into P1, raw barriers ----
  for (int c = 0; c < 4; ++c){
    *(bfx8*)(LDS +         lr    *64 + lc*8) = cwh0;
    *(bfx8*)(LDS +        (lr+32)*64 + lc*8) = cwh1;
    *(bfx8*)(LDS + 4096 +  lr    *64 + lc*8) = cwl0;
    *(bfx8*)(LDS + 4096 + (lr+32)*64 + lc*8) = cwl1;
    *(bfx8*)(LDS + 8192 +  lr    *64 + lc*8) = cah0;
    *(bfx8*)(LDS + 8192 + (lr+32)*64 + lc*8) = cah1;
    *(bfx8*)(LDS + 12288 + lr    *64 + lc*8) = cal0;
    *(bfx8*)(LDS + 12288 +(lr+32)*64 + lc*8) = cal1;
    WAITLG(0); SBAR();
    if (c < 3) LOADRAW((c + 1)*64);
    Frags f0, f1;
    rdf(LDS, 0, f0);
    rdf(LDS, 1, f1);
    WAITLG(8);
    mm12(f0);
    WAITLG(0); SBAR();
    if (c < 3) CVT();
    mm12(f1);
  }

  // ---- phase 2: chunks 4..19, depth-3 ring, counted vmcnt ----
  int bi = 0;
  for (int i = 4; i <= 19; ++i){
    if (i < 18)      { WAITVM(16); }
    else if (i == 18){ WAITVM(8); }
    else             { WAITVM(0); }
    SBAR();                                  // chunk i staged by all waves
    const ushort_t* buf = LDS + 16384 + bi*16384;
    Frags f0, f1;
    rdf(buf, 0, f0);
    rdf(buf, 1, f1);
    WAITLG(8);
    mm12(f0);
    WAITLG(0); SBAR();                       // all reads done -> buf free
    if (i <= 16) ISSUE(i + 3, bi);
    mm12(f1);
    bi = (bi == 2) ? 0 : bi + 1;
  }

  // ---- epilogue: gates -> c (regs), h -> global hi/lo planes ----
#pragma unroll
  for (int m = 0; m < 2; ++m){
    const int n = n0 + wm*8 + m*4 + cb;
    const float bi_ = bias[n];
    const float bf_ = bias[1024 + n];
    const float bg_ = bias[2048 + n];
    const float bo_ = bias[3072 + n];
#pragma unroll
    for (int nb = 0; nb < 2; ++nb){
      const int b = b0 + wn*32 + nb*16 + fr;
      float gi = acc[m][nb][0] + bi_;
      float gf = acc[m][nb][1] + bf_;
      float gg = acc[m][nb][2] + bg_;
      float go = acc[m][nb][3] + bo_;
      float c_new = sigm(gf)*creg[m][nb] + sigm(gi)*tanh_(gg);
      float h_new = sigm(go)*tanh_(c_new);
      creg[m][nb] = c_new;
      unsigned short hi = f2bf(h_new);
      outh[(size_t)b*2048 + n] = hi;
      outl[(size_t)b*2048 + n] = f2bf(h_new - bf2f(hi));
    }
  }
}

// ---------------------------------------------------------------------------
// MLP GEMM: 256 WGs = 16 d-tiles x 8 b-tiles x 2 K-halves; each wave a K=256
// strip, wave-private LDS staging (no inner barriers). Partials -> Part.
// ---------------------------------------------------------------------------
__device__ __forceinline__ void mlp_gemm(
    const ushort_t* __restrict__ hch, const ushort_t* __restrict__ hcl,
    const ushort_t* __restrict__ mWh, const ushort_t* __restrict__ mWl,
    float* __restrict__ Part, int wg, ushort_t* LDS)
{
  const int tid = threadIdx.x, lane = tid & 63, wv = tid >> 6;
  const int cb = lane >> 4, fr = lane & 15, sx = fr & 7;
  const int wgl = wg & 127, kh = wg >> 7;
  const int d0 = (wgl >> 3)*16, b0 = (wgl & 7)*16;
  const int kb = kh*1024 + wv*256;
  const int srw = lane >> 3, sg = (lane & 7) ^ srw;

  const ushort_t* ps[4] = { mWh, mWl, hch, hcl };
  const int pr0[4] = { d0, d0, b0, b0 };
  const ushort_t* pj[4][2];
#pragma unroll
  for (int p = 0; p < 4; ++p)
#pragma unroll
    for (int j = 0; j < 2; ++j)
      pj[p][j] = ps[p] + (size_t)(pr0[p] + j*8 + srw)*2048 + kb + sg*8;
  ushort_t* lb[3];
#pragma unroll
  for (int bp = 0; bp < 3; ++bp)
    lb[bp] = LDS + 16384 + (wv*3 + bp)*4096;

  auto ISSUE = [&](int c, int bp){
    const int ko = c*64;
#pragma unroll
    for (int p = 0; p < 4; ++p)
#pragma unroll
      for (int j = 0; j < 2; ++j)
        stage16(pj[p][j] + ko, lb[bp] + p*1024 + j*512);
  };
  ISSUE(0, 0); ISSUE(1, 1); ISSUE(2, 2);

  f32x4 acc = {};
  int bp = 0;
  for (int c = 0; c < 4; ++c){
    if (c < 2)      { WAITVM(16); }
    else if (c == 2){ WAITVM(8); }
    else            { WAITVM(0); }
    const ushort_t* B = lb[bp];
    const int ga0 = ((cb) ^ sx) << 3;
    const int ga1 = ((4 + cb) ^ sx) << 3;
    bfx8 wh0 = *(const bfx8*)(B +        fr*64 + ga0);
    bfx8 wl0 = *(const bfx8*)(B + 1024 + fr*64 + ga0);
    bfx8 ah0 = *(const bfx8*)(B + 2048 + fr*64 + ga0);
    bfx8 al0 = *(const bfx8*)(B + 3072 + fr*64 + ga0);
    bfx8 wh1 = *(const bfx8*)(B +        fr*64 + ga1);
    bfx8 wl1 = *(const bfx8*)(B + 1024 + fr*64 + ga1);
    bfx8 ah1 = *(const bfx8*)(B + 2048 + fr*64 + ga1);
    bfx8 al1 = *(const bfx8*)(B + 3072 + fr*64 + ga1);
    WAITLG(0);
    if (c == 0) ISSUE(3, 0);
    acc = MFMA(wh0, ah0, acc); acc = MFMA(wh0, al0, acc); acc = MFMA(wl0, ah0, acc);
    acc = MFMA(wh1, ah1, acc); acc = MFMA(wh1, al1, acc); acc = MFMA(wl1, ah1, acc);
    bp = (bp == 2) ? 0 : bp + 1;
  }
  ((f32x4*)Part)[(((size_t)wgl*2 + kh)*4 + wv)*64 + lane] = acc;
}

// Combine partials: 128 WGs (wave 0 only), write dout + next input planes.
__device__ __forceinline__ void mlp_combine(
    const float* __restrict__ Part, const float* __restrict__ mb,
    float* __restrict__ dout,
    ushort_t* __restrict__ inph, ushort_t* __restrict__ inpl, int wg, int t)
{
  if (threadIdx.x >= 64) return;
  const int lane = threadIdx.x;
  const int d0 = (wg >> 3)*16, b0 = (wg & 7)*16;
  const int cb = lane >> 4, fr = lane & 15;
  const f32x4* P4 = (const f32x4*)Part;
  f32x4 s = {};
#pragma unroll
  for (int kh = 0; kh < 2; ++kh)
#pragma unroll
    for (int wv = 0; wv < 4; ++wv)
      s += P4[(((size_t)wg*2 + kh)*4 + wv)*64 + lane];
  const int dr = d0 + cb*4, b = b0 + fr;
  s += *(const f32x4*)&mb[dr];
  *(f32x4*)&dout[((size_t)b*128 + t)*256 + dr] = s;
  u16x4 hv, lv;
#pragma unroll
  for (int j = 0; j < 4; ++j){
    hv[j] = f2bf(s[j]);
    lv[j] = f2bf(s[j] - bf2f(hv[j]));
  }
  *(u16x4*)&inph[(size_t)b*256 + dr] = hv;
  *(u16x4*)&inpl[(size_t)b*256 + dr] = lv;
}

// WG -> (dir, rowgroup, b-half); b-halves 8 apart => same XCD (round-robin).
__device__ __forceinline__ void wg_decode(int wg, int& dir, int& r0, int& n0,
                                          int& b0, int& me){
  const int half = (wg >> 3) & 1;
  const int rgd  = (wg & 7) | ((wg >> 4) << 3);        // 0..127
  dir = rgd >> 6;
  const int rg = rgd & 63;
  r0 = rg * 64; n0 = rg * 16; b0 = half * 64;
  me = (rg << 1) | half;                               // 0..127 within dir
}

__global__ void __launch_bounds__(256) rnn_enc_kernel(
    const float* __restrict__ Wih_f, const float* __restrict__ b_f,
    const float* __restrict__ Wih_b, const float* __restrict__ b_b,
    const ushort_t* __restrict__ WhhH, const ushort_t* __restrict__ WhhL,
    const float* __restrict__ x,
    ushort_t* __restrict__ Hh, ushort_t* __restrict__ Hl,
    float* __restrict__ C, unsigned* flagsE)
{
  extern __shared__ ushort_t LDS[];
  int dir, r0, n0, b0, me;
  wg_decode(blockIdx.x, dir, r0, n0, b0, me);
  const float* Wih = dir ? Wih_b : Wih_f;
  const float* bia = dir ? b_b : b_f;
  const ushort_t* WhH = WhhH + (size_t)dir*4096*1024;
  const ushort_t* WhL = WhhL + (size_t)dir*4096*1024;
  unsigned* fl = flagsE + dir*128;
  float creg[2][2] = {{0.f, 0.f}, {0.f, 0.f}};
  unsigned gen = 0;
  for (int t = 0; t < 256; ++t){
    const int tt = dir ? (255 - t) : t;
    const int rp = t & 1;
    cell_step<1>(Wih, WhH, WhL, bia,
                 x + (size_t)tt*256, nullptr, nullptr,
                 Hh + (size_t)rp     *262144 + dir*1024,
                 Hl + (size_t)rp     *262144 + dir*1024,
                 Hh + (size_t)(rp^1) *262144 + dir*1024,
                 Hl + (size_t)(rp^1) *262144 + dir*1024,
                 creg, r0, n0, b0, LDS);
    ++gen;
    bar(fl, 128, me, gen);
  }
  // hand off c-state to decoder
  {
    const int lane = threadIdx.x & 63, wv = threadIdx.x >> 6;
    const int wm = wv >> 1, wn = wv & 1, cb = lane >> 4, fr = lane & 15;
    float* Cst = C + (size_t)dir*1024*128;
#pragma unroll
    for (int m = 0; m < 2; ++m)
#pragma unroll
      for (int nb = 0; nb < 2; ++nb){
        const int n = n0 + wm*8 + m*4 + cb;
        const int b = b0 + wn*32 + nb*16 + fr;
        Cst[n*128 + b] = creg[m][nb];
      }
  }
}

__global__ void __launch_bounds__(256) rnn_dec_kernel(
    const float* __restrict__ Wih_f, const float* __restrict__ b_f,
    const float* __restrict__ Wih_b, const float* __restrict__ b_b,
    const ushort_t* __restrict__ WhhH, const ushort_t* __restrict__ WhhL,
    const ushort_t* __restrict__ mWh, const ushort_t* __restrict__ mWl,
    const float* __restrict__ mb,
    ushort_t* __restrict__ Hh, ushort_t* __restrict__ Hl,
    float* __restrict__ C,
    ushort_t* __restrict__ inph, ushort_t* __restrict__ inpl,
    float* __restrict__ Part,
    float* __restrict__ dout, unsigned* flagsD)
{
  extern __shared__ ushort_t LDS[];
  const int wg = blockIdx.x;
  int dir, r0, n0, b0, me;
  wg_decode(wg, dir, r0, n0, b0, me);
  const float* Wih = dir ? Wih_b : Wih_f;
  const float* bia = dir ? b_b : b_f;
  const ushort_t* WhH = WhhH + (size_t)dir*4096*1024;
  const ushort_t* WhL = WhhL + (size_t)dir*4096*1024;
  float creg[2][2];
  {
    const int lane = threadIdx.x & 63, wv = threadIdx.x >> 6;
    const int wm = wv >> 1, wn = wv & 1, cb = lane >> 4, fr = lane & 15;
    const float* Cst = C + (size_t)dir*1024*128;
#pragma unroll
    for (int m = 0; m < 2; ++m)
#pragma unroll
      for (int nb = 0; nb < 2; ++nb){
        const int n = n0 + wm*8 + m*4 + cb;
        const int b = b0 + wn*32 + nb*16 + fr;
        creg[m][nb] = Cst[n*128 + b];
      }
  }
  for (int t = 0; t < 128; ++t){
    const int rp = t & 1;
    cell_step<0>(Wih, WhH, WhL, bia,
                 nullptr, inph, inpl,
                 Hh + (size_t)rp     *262144 + dir*1024,
                 Hl + (size_t)rp     *262144 + dir*1024,
                 Hh + (size_t)(rp^1) *262144 + dir*1024,
                 Hl + (size_t)(rp^1) *262144 + dir*1024,
                 creg, r0, n0, b0, LDS);
    bar(flagsD, 256, wg, (unsigned)(3*t + 1));
    mlp_gemm(Hh + (size_t)(rp^1)*262144, Hl + (size_t)(rp^1)*262144,
             mWh, mWl, Part, wg, LDS);
    bar(flagsD, 256, wg, (unsigned)(3*t + 2));
    if (wg < 128) mlp_combine(Part, mb, dout, inph, inpl, wg, t);
    bar(flagsD, 256, wg, (unsigned)(3*t + 3));
  }
}

// ---------------------------------------------------------------------------
// Prep kernels
// ---------------------------------------------------------------------------
__global__ void k_wplanes(ushort_t* Hp, ushort_t* Lp,
                          const float* Whh_f, const float* Whh_b)
{
  const size_t N = 2ull*4096*1024;
  for (size_t i = (size_t)blockIdx.x*blockDim.x + threadIdx.x; i < N;
       i += (size_t)gridDim.x*blockDim.x){
    int dir = (int)(i >> 22);
    int r   = (int)((i >> 10) & 4095);
    int k   = (int)(i & 1023);
    int n = r >> 2, q = r & 3;
    const float* W = dir ? Whh_b : Whh_f;
    float v = W[(size_t)(q*1024 + n)*1024 + k];
    unsigned short h = f2bf(v);
    Hp[i] = h;
    Lp[i] = f2bf(v - bf2f(h));
  }
}

__global__ void k_init(ushort_t* Hh, ushort_t* Hl,
                       ushort_t* inph, ushort_t* inpl,
                       ushort_t* mWh, ushort_t* mWl,
                       const float* x, const float* mW, unsigned* cnt)
{
  const size_t N = 524288;  // 2 parity * 128 * 2048 == 256*2048 (mlp)
  for (size_t i = (size_t)blockIdx.x*blockDim.x + threadIdx.x; i < N;
       i += (size_t)gridDim.x*blockDim.x){
    Hh[i] = 0; Hl[i] = 0;
    float wv = mW[i];
    unsigned short wh = f2bf(wv);
    mWh[i] = wh;
    mWl[i] = f2bf(wv - bf2f(wh));
    if (i < 32768){
      int b = (int)(i >> 8), d = (int)(i & 255);
      float v = x[((size_t)b*256 + 255)*256 + d];        // x[:, 255, :]
      unsigned short hi = f2bf(v);
      inph[i] = hi;
      inpl[i] = f2bf(v - bf2f(hi));
    }
    if (i < 1024) cnt[i] = 0;
  }
}

// ---------------------------------------------------------------------------
extern "C" void kernel_launch(void* const* d_in, const int* in_sizes, int n_in,
                              void* d_out, int out_size, void* d_ws, size_t ws_size,
                              hipStream_t stream)
{
  (void)in_sizes; (void)n_in; (void)out_size; (void)ws_size;
  const float* x      = (const float*)d_in[0];
  const float* eWih_f = (const float*)d_in[2];
  const float* eWhh_f = (const float*)d_in[3];
  const float* eb_f   = (const float*)d_in[4];
  const float* eWih_b = (const float*)d_in[5];
  const float* eWhh_b = (const float*)d_in[6];
  const float* eb_b   = (const float*)d_in[7];
  const float* dWih_f = (const float*)d_in[8];
  const float* dWhh_f = (const float*)d_in[9];
  const float* db_f   = (const float*)d_in[10];
  const float* dWih_b = (const float*)d_in[11];
  const float* dWhh_b = (const float*)d_in[12];
  const float* db_b   = (const float*)d_in[13];
  const float* mW     = (const float*)d_in[14];
  const float* mb     = (const float*)d_in[15];

  char* p = (char*)d_ws;
  size_t off = 0;
  unsigned* cnt   = (unsigned*)(p + off);  off += 4096;      // flagsD[256], flagsE[256]
  ushort_t* WhhEh = (ushort_t*)(p + off);  off += 16777216;
  ushort_t* WhhEl = (ushort_t*)(p + off);  off += 16777216;
  ushort_t* WhhDh = (ushort_t*)(p + off);  off += 16777216;
  ushort_t* WhhDl = (ushort_t*)(p + off);  off += 16777216;
  ushort_t* mWh   = (ushort_t*)(p + off);  off += 1048576;
  ushort_t* mWl   = (ushort_t*)(p + off);  off += 1048576;
  ushort_t* Hh    = (ushort_t*)(p + off);  off += 1048576;
  ushort_t* Hl    = (ushort_t*)(p + off);  off += 1048576;
  float*    C     = (float*)(p + off);     off += 1048576;
  ushort_t* inph  = (ushort_t*)(p + off);  off += 65536;
  ushort_t* inpl  = (ushort_t*)(p + off);  off += 65536;
  float*    Part  = (float*)(p + off);     off += 1048576;   // 128*2*4*64 f32x4

  unsigned* flagsD = cnt;
  unsigned* flagsE = cnt + 256;

  hipFuncSetAttribute(reinterpret_cast<const void*>(rnn_enc_kernel),
                      hipFuncAttributeMaxDynamicSharedMemorySize, 131072);
  hipFuncSetAttribute(reinterpret_cast<const void*>(rnn_dec_kernel),
                      hipFuncAttributeMaxDynamicSharedMemorySize, 131072);

  k_init   <<<512, 256, 0, stream>>>(Hh, Hl, inph, inpl, mWh, mWl, x, mW, cnt);
  k_wplanes<<<2048, 256, 0, stream>>>(WhhEh, WhhEl, eWhh_f, eWhh_b);
  k_wplanes<<<2048, 256, 0, stream>>>(WhhDh, WhhDl, dWhh_f, dWhh_b);

  rnn_enc_kernel<<<NWG, 256, 131072, stream>>>(eWih_f, eb_f, eWih_b, eb_b,
                                               WhhEh, WhhEl, x, Hh, Hl, C, flagsE);
  rnn_dec_kernel<<<NWG, 256, 131072, stream>>>(dWih_f, db_f, dWih_b, db_b,
                                               WhhDh, WhhDl, mWh, mWl, mb,
                                               Hh, Hl, C, inph, inpl, Part,
                                               (float*)d_out, flagsD);
}

// Round 7
// 10120.766 us; speedup vs baseline: 3.2902x; 1.6118x over previous
//
#include <hip/hip_runtime.h>
#include <stdint.h>

// ---------------------------------------------------------------------------
// SimpleRNN: bidirectional LSTM encoder (S=256) + autoregressive decoder (T=128)
// B=128, D=256, H=1024. Persistent kernels, FENCE-FREE flag grid barriers:
// all mutable cross-WG data (h, inp, Part, flags) goes through agent-coherent
// (sc0|sc1, L3-serviced) accesses; immutable weights stay L2-cached and are
// never invalidated (no __threadfence anywhere in the persistent loops).
// 3-term split-bf16 MFMA (Wh*Ah + Wh*Al + Wl*Ah), f32 accum/gates.
// ---------------------------------------------------------------------------

typedef __attribute__((ext_vector_type(8))) short bfx8;
typedef __attribute__((ext_vector_type(4))) float f32x4;
typedef __attribute__((ext_vector_type(4))) unsigned short u16x4;
typedef unsigned short ushort_t;
typedef unsigned long long u64;

#define NWG 256
#define MFMA(a,b,c) __builtin_amdgcn_mfma_f32_16x16x32_bf16((a),(b),(c),0,0,0)
#define WAITVM(N) { asm volatile("s_waitcnt vmcnt(" #N ")" ::: "memory"); __builtin_amdgcn_sched_barrier(0); }
#define WAITLG(N) { asm volatile("s_waitcnt lgkmcnt(" #N ")" ::: "memory"); __builtin_amdgcn_sched_barrier(0); }
#define SBAR()    { __builtin_amdgcn_s_barrier(); __builtin_amdgcn_sched_barrier(0); }

__device__ __forceinline__ unsigned short f2bf(float f){
  unsigned u = __float_as_uint(f);
  u += 0x7FFFu + ((u >> 16) & 1u);          // round-to-nearest-even
  return (unsigned short)(u >> 16);
}
__device__ __forceinline__ float bf2f(unsigned short h){
  return __uint_as_float(((unsigned)h) << 16);
}
__device__ __forceinline__ float sigm(float x){ return 1.f/(1.f + __expf(-x)); }
__device__ __forceinline__ float tanh_(float x){ return 1.f - 2.f/(__expf(2.f*x) + 1.f); }

// plain (L2-cached) async global->LDS: immutable data only
__device__ __forceinline__ void stage16(const void* g, void* l){
  __builtin_amdgcn_global_load_lds((const __attribute__((address_space(1))) void*)g,
                                   (__attribute__((address_space(3))) void*)l,
                                   16, 0, 0);
}
// agent-coherent async global->LDS (CPol SC0|SC1 = 0x11): mutable cross-WG data
__device__ __forceinline__ void stage16c(const void* g, void* l){
  __builtin_amdgcn_global_load_lds((const __attribute__((address_space(1))) void*)g,
                                   (__attribute__((address_space(3))) void*)l,
                                   16, 0, 0x11);
}

// coherent 16B load (2 x u64 agent-relaxed atomics)
__device__ __forceinline__ bfx8 ld16c(const ushort_t* p){
  const u64* q = (const u64*)p;
  u64 a = __hip_atomic_load(q,     __ATOMIC_RELAXED, __HIP_MEMORY_SCOPE_AGENT);
  u64 b = __hip_atomic_load(q + 1, __ATOMIC_RELAXED, __HIP_MEMORY_SCOPE_AGENT);
  union { u64 u[2]; bfx8 v; } x; x.u[0] = a; x.u[1] = b; return x.v;
}
__device__ __forceinline__ void sth2(ushort_t* p, unsigned short v){
  __hip_atomic_store(p, v, __ATOMIC_RELAXED, __HIP_MEMORY_SCOPE_AGENT);
}

// two f32x4 (8 consecutive f32) -> hi/lo bf16 planes
__device__ __forceinline__ void cvt2(const f32x4& a, const f32x4& b, bfx8& hi, bfx8& lo){
#pragma unroll
  for (int j = 0; j < 4; ++j){
    unsigned short h0 = f2bf(a[j]);
    unsigned short h1 = f2bf(b[j]);
    hi[j]   = (short)h0; lo[j]   = (short)f2bf(a[j] - bf2f(h0));
    hi[4+j] = (short)h1; lo[4+j] = (short)f2bf(b[j] - bf2f(h1));
  }
}

// ---------------------------------------------------------------------------
// Fence-free grid barrier: flag store (agent-coherent) after syncthreads'
// vmcnt drain; wave0 spin-scans flags with relaxed agent loads. NO cache
// invalidation -> L2 weight residency survives the barrier.
// ---------------------------------------------------------------------------
__device__ __forceinline__ void bar(unsigned* flags, int nflags, int me, unsigned gen){
  __syncthreads();                       // drains vmcnt(0): all sc1 stores done
  if (threadIdx.x == 0)
    __hip_atomic_store(&flags[me], gen, __ATOMIC_RELAXED, __HIP_MEMORY_SCOPE_AGENT);
  if (threadIdx.x < 64){
    const int l = threadIdx.x;
    for (;;){
      unsigned mn = 0xFFFFFFFFu;
      for (int o = l; o < nflags; o += 64){
        unsigned v = __hip_atomic_load(&flags[o], __ATOMIC_RELAXED, __HIP_MEMORY_SCOPE_AGENT);
        mn = mn < v ? mn : v;
      }
      if (__all((int)(mn >= gen))) break;
      __builtin_amdgcn_s_sleep(1);
    }
  }
  __syncthreads();
}

struct Frags { bfx8 awh0, awh1, awl0, awl1, bh0, bh1, bl0, bl1; };

// ---------------------------------------------------------------------------
// One LSTM cell step. WG owns 64 gate-interleaved W-rows' (16 neurons) x 64
// batches. Phase 1 (k<256, 4 chunks): register-staged (f32 cvt / coherent inp).
// Phase 2 (k in [256,1280), 16 chunks): global_load_lds depth-3 ring, counted
// vmcnt; weight planes plain (L2-cached), h planes coherent (sc0|sc1).
// LDS (ushort units): P1 planes @0/4096/8192/12288; ring buf bp @16384+bp*16384.
// ---------------------------------------------------------------------------
template<int ENC>
__device__ __forceinline__ void cell_step(
    const float*    __restrict__ Wih,   // [4096][256] f32 original (this dir)
    const ushort_t* __restrict__ WhH,   // [4096][1024] bf16 hi (this dir)
    const ushort_t* __restrict__ WhL,   // lo
    const float*    __restrict__ bias,  // [4096] f32 (original order)
    const float*    __restrict__ xsl,   // ENC: x + tt*256 (row stride 65536)
    const ushort_t* __restrict__ iph,   // DEC: [128][256] hi
    const ushort_t* __restrict__ ipl,   // DEC: lo
    const ushort_t* __restrict__ hh,    // h hi (base + dir*1024), stride 2048
    const ushort_t* __restrict__ hl,    // h lo
    ushort_t* __restrict__ outh, ushort_t* __restrict__ outl,
    float (&creg)[2][2],
    int r0, int n0, int b0, ushort_t* LDS)
{
  const int tid  = threadIdx.x;
  const int lane = tid & 63;
  const int wv   = tid >> 6;
  const int wm   = wv >> 1, wn = wv & 1;
  const int lr   = tid >> 3;               // phase-1 staging row 0..31
  const int lc   = tid & 7;
  const int cb   = lane >> 4;
  const int fr   = lane & 15;
  const int sc8  = lc ^ (lr & 7);          // phase-1 pre-swizzled source chunk
  const int sx   = fr & 7;
  const int rwa0 = wm*32 + fr, rwa1 = rwa0 + 16;
  const int rwb0 = wn*32 + fr, rwb1 = rwb0 + 16;

  // ---- phase-1 source pointers (rows r0+lr, r0+32+lr; gate-interleaved) ----
  const int ra = r0 + lr, rb = ra + 32;
  const float* wih0 = Wih + (size_t)((ra & 3)*1024 + (ra >> 2))*256 + sc8*8;
  const float* wih1 = Wih + (size_t)((rb & 3)*1024 + (rb >> 2))*256 + sc8*8;
  const float *xs0 = nullptr, *xs1 = nullptr;
  const ushort_t *ih0 = nullptr, *ih1 = nullptr, *il0 = nullptr, *il1 = nullptr;
  if (ENC){
    xs0 = xsl + (size_t)(b0 + lr)*65536 + sc8*8;
    xs1 = xs0 + (size_t)32*65536;
  } else {
    ih0 = iph + (size_t)(b0 + lr)*256 + sc8*8;  ih1 = ih0 + 32*256;
    il0 = ipl + (size_t)(b0 + lr)*256 + sc8*8;  il1 = il0 + 32*256;
  }

  // ---- phase-2 staging bases: wave wv stages plane wv ----
  const ushort_t* sb; size_t sstr; int srow0;
  if      (wv == 0){ sb = WhH; sstr = 1024; srow0 = r0; }
  else if (wv == 1){ sb = WhL; sstr = 1024; srow0 = r0; }
  else if (wv == 2){ sb = hh;  sstr = 2048; srow0 = b0; }
  else             { sb = hl;  sstr = 2048; srow0 = b0; }
  const int srw = lane >> 3;
  const int sg  = (lane & 7) ^ srw;        // swizzled source granule
  const ushort_t* pj[8];
#pragma unroll
  for (int j = 0; j < 8; ++j)
    pj[j] = sb + (size_t)(srow0 + j*8 + srw)*sstr + sg*8;
  ushort_t* ldsb[3];
#pragma unroll
  for (int bp = 0; bp < 3; ++bp)
    ldsb[bp] = LDS + 16384 + bp*16384 + wv*4096;

  auto ISSUE = [&](int c, int bp){
    const int ko = (c - 4)*64;
    if (wv < 2){
#pragma unroll
      for (int j = 0; j < 8; ++j)
        stage16(pj[j] + ko, ldsb[bp] + j*512);     // weights: L2-cached
    } else {
#pragma unroll
      for (int j = 0; j < 8; ++j)
        stage16c(pj[j] + ko, ldsb[bp] + j*512);    // h: agent-coherent
    }
  };

  f32x4 acc[2][2] = {};
  auto rdf = [&](const ushort_t* buf, int ks, Frags& f){
    const int ga = (((ks << 2) + cb) ^ sx) << 3;
    f.awh0 = *(const bfx8*)(buf +         rwa0*64 + ga);
    f.awh1 = *(const bfx8*)(buf +         rwa1*64 + ga);
    f.awl0 = *(const bfx8*)(buf + 4096  + rwa0*64 + ga);
    f.awl1 = *(const bfx8*)(buf + 4096  + rwa1*64 + ga);
    f.bh0  = *(const bfx8*)(buf + 8192  + rwb0*64 + ga);
    f.bh1  = *(const bfx8*)(buf + 8192  + rwb1*64 + ga);
    f.bl0  = *(const bfx8*)(buf + 12288 + rwb0*64 + ga);
    f.bl1  = *(const bfx8*)(buf + 12288 + rwb1*64 + ga);
  };
  auto mm12 = [&](const Frags& f){
    acc[0][0] = MFMA(f.awh0, f.bh0, acc[0][0]);
    acc[0][0] = MFMA(f.awh0, f.bl0, acc[0][0]);
    acc[0][0] = MFMA(f.awl0, f.bh0, acc[0][0]);
    acc[0][1] = MFMA(f.awh0, f.bh1, acc[0][1]);
    acc[0][1] = MFMA(f.awh0, f.bl1, acc[0][1]);
    acc[0][1] = MFMA(f.awl0, f.bh1, acc[0][1]);
    acc[1][0] = MFMA(f.awh1, f.bh0, acc[1][0]);
    acc[1][0] = MFMA(f.awh1, f.bl0, acc[1][0]);
    acc[1][0] = MFMA(f.awl1, f.bh0, acc[1][0]);
    acc[1][1] = MFMA(f.awh1, f.bh1, acc[1][1]);
    acc[1][1] = MFMA(f.awh1, f.bl1, acc[1][1]);
    acc[1][1] = MFMA(f.awl1, f.bh1, acc[1][1]);
  };

  // ---- phase-1 raw loads / cvt ----
  f32x4 rw0a, rw0b, rw1a, rw1b, rxa0, rxb0, rxa1, rxb1;
  bfx8 cwh0, cwh1, cwl0, cwl1, cah0, cah1, cal0, cal1;
  auto LOADRAW = [&](int kc){
    rw0a = *(const f32x4*)(wih0 + kc);  rw0b = *(const f32x4*)(wih0 + kc + 4);
    rw1a = *(const f32x4*)(wih1 + kc);  rw1b = *(const f32x4*)(wih1 + kc + 4);
    if (ENC){
      rxa0 = *(const f32x4*)(xs0 + kc); rxb0 = *(const f32x4*)(xs0 + kc + 4);
      rxa1 = *(const f32x4*)(xs1 + kc); rxb1 = *(const f32x4*)(xs1 + kc + 4);
    } else {
      cah0 = ld16c(ih0 + kc);  cah1 = ld16c(ih1 + kc);   // coherent inp
      cal0 = ld16c(il0 + kc);  cal1 = ld16c(il1 + kc);
    }
  };
  auto CVT = [&](){
    cvt2(rw0a, rw0b, cwh0, cwl0);
    cvt2(rw1a, rw1b, cwh1, cwl1);
    if (ENC){ cvt2(rxa0, rxb0, cah0, cal0); cvt2(rxa1, rxb1, cah1, cal1); }
  };

  LOADRAW(0);
  ISSUE(4, 0); ISSUE(5, 1); ISSUE(6, 2);     // phase-2 prologue (24 in flight)
  CVT();

  // ---- phase 1: chunks 0..3, register-staged into P1, raw barriers ----
  for (int c = 0; c < 4; ++c){
    *(bfx8*)(LDS +         lr    *64 + lc*8) = cwh0;
    *(bfx8*)(LDS +        (lr+32)*64 + lc*8) = cwh1;
    *(bfx8*)(LDS + 4096 +  lr    *64 + lc*8) = cwl0;
    *(bfx8*)(LDS + 4096 + (lr+32)*64 + lc*8) = cwl1;
    *(bfx8*)(LDS + 8192 +  lr    *64 + lc*8) = cah0;
    *(bfx8*)(LDS + 8192 + (lr+32)*64 + lc*8) = cah1;
    *(bfx8*)(LDS + 12288 + lr    *64 + lc*8) = cal0;
    *(bfx8*)(LDS + 12288 +(lr+32)*64 + lc*8) = cal1;
    WAITLG(0); SBAR();
    if (c < 3) LOADRAW((c + 1)*64);
    Frags f0, f1;
    rdf(LDS, 0, f0);
    rdf(LDS, 1, f1);
    WAITLG(8);
    mm12(f0);
    WAITLG(0); SBAR();
    if (c < 3) CVT();
    mm12(f1);
  }

  // ---- phase 2: chunks 4..19, depth-3 ring, counted vmcnt ----
  int bi = 0;
  for (int i = 4; i <= 19; ++i){
    if (i < 18)      { WAITVM(16); }
    else if (i == 18){ WAITVM(8); }
    else             { WAITVM(0); }
    SBAR();                                  // chunk i staged by all waves
    const ushort_t* buf = LDS + 16384 + bi*16384;
    Frags f0, f1;
    rdf(buf, 0, f0);
    rdf(buf, 1, f1);
    WAITLG(8);
    mm12(f0);
    WAITLG(0); SBAR();                       // all reads done -> buf free
    if (i <= 16) ISSUE(i + 3, bi);
    mm12(f1);
    bi = (bi == 2) ? 0 : bi + 1;
  }

  // ---- epilogue: gates -> c (regs), h -> global hi/lo planes (coherent) ----
#pragma unroll
  for (int m = 0; m < 2; ++m){
    const int n = n0 + wm*8 + m*4 + cb;
    const float bi_ = bias[n];
    const float bf_ = bias[1024 + n];
    const float bg_ = bias[2048 + n];
    const float bo_ = bias[3072 + n];
#pragma unroll
    for (int nb = 0; nb < 2; ++nb){
      const int b = b0 + wn*32 + nb*16 + fr;
      float gi = acc[m][nb][0] + bi_;
      float gf = acc[m][nb][1] + bf_;
      float gg = acc[m][nb][2] + bg_;
      float go = acc[m][nb][3] + bo_;
      float c_new = sigm(gf)*creg[m][nb] + sigm(gi)*tanh_(gg);
      float h_new = sigm(go)*tanh_(c_new);
      creg[m][nb] = c_new;
      unsigned short hi = f2bf(h_new);
      sth2(&outh[(size_t)b*2048 + n], hi);
      sth2(&outl[(size_t)b*2048 + n], f2bf(h_new - bf2f(hi)));
    }
  }
}

// ---------------------------------------------------------------------------
// MLP GEMM: 256 WGs = 16 d-tiles x 8 b-tiles x 2 K-halves; each wave a K=256
// strip, wave-private LDS staging (no inner barriers). Partials -> Part (sc1).
// ---------------------------------------------------------------------------
__device__ __forceinline__ void mlp_gemm(
    const ushort_t* __restrict__ hch, const ushort_t* __restrict__ hcl,
    const ushort_t* __restrict__ mWh, const ushort_t* __restrict__ mWl,
    float* __restrict__ Part, int wg, ushort_t* LDS)
{
  const int tid = threadIdx.x, lane = tid & 63, wv = tid >> 6;
  const int cb = lane >> 4, fr = lane & 15, sx = fr & 7;
  const int wgl = wg & 127, kh = wg >> 7;
  const int d0 = (wgl >> 3)*16, b0 = (wgl & 7)*16;
  const int kb = kh*1024 + wv*256;
  const int srw = lane >> 3, sg = (lane & 7) ^ srw;

  const ushort_t* ps[4] = { mWh, mWl, hch, hcl };
  const int pr0[4] = { d0, d0, b0, b0 };
  const ushort_t* pj[4][2];
#pragma unroll
  for (int p = 0; p < 4; ++p)
#pragma unroll
    for (int j = 0; j < 2; ++j)
      pj[p][j] = ps[p] + (size_t)(pr0[p] + j*8 + srw)*2048 + kb + sg*8;
  ushort_t* lb[3];
#pragma unroll
  for (int bp = 0; bp < 3; ++bp)
    lb[bp] = LDS + 16384 + (wv*3 + bp)*4096;

  auto ISSUE = [&](int c, int bp){
    const int ko = c*64;
#pragma unroll
    for (int p = 0; p < 4; ++p)
#pragma unroll
      for (int j = 0; j < 2; ++j){
        if (p < 2) stage16 (pj[p][j] + ko, lb[bp] + p*1024 + j*512);  // weights
        else       stage16c(pj[p][j] + ko, lb[bp] + p*1024 + j*512);  // h
      }
  };
  ISSUE(0, 0); ISSUE(1, 1); ISSUE(2, 2);

  f32x4 acc = {};
  int bp = 0;
  for (int c = 0; c < 4; ++c){
    if (c < 2)      { WAITVM(16); }
    else if (c == 2){ WAITVM(8); }
    else            { WAITVM(0); }
    const ushort_t* B = lb[bp];
    const int ga0 = ((cb) ^ sx) << 3;
    const int ga1 = ((4 + cb) ^ sx) << 3;
    bfx8 wh0 = *(const bfx8*)(B +        fr*64 + ga0);
    bfx8 wl0 = *(const bfx8*)(B + 1024 + fr*64 + ga0);
    bfx8 ah0 = *(const bfx8*)(B + 2048 + fr*64 + ga0);
    bfx8 al0 = *(const bfx8*)(B + 3072 + fr*64 + ga0);
    bfx8 wh1 = *(const bfx8*)(B +        fr*64 + ga1);
    bfx8 wl1 = *(const bfx8*)(B + 1024 + fr*64 + ga1);
    bfx8 ah1 = *(const bfx8*)(B + 2048 + fr*64 + ga1);
    bfx8 al1 = *(const bfx8*)(B + 3072 + fr*64 + ga1);
    WAITLG(0);
    if (c == 0) ISSUE(3, 0);
    acc = MFMA(wh0, ah0, acc); acc = MFMA(wh0, al0, acc); acc = MFMA(wl0, ah0, acc);
    acc = MFMA(wh1, ah1, acc); acc = MFMA(wh1, al1, acc); acc = MFMA(wl1, ah1, acc);
    bp = (bp == 2) ? 0 : bp + 1;
  }
  // coherent partial store (2 x u64)
  u64* P8 = (u64*)Part;
  const size_t idx = (((size_t)wgl*2 + kh)*4 + wv)*64 + lane;
  u64 a = ((u64)__float_as_uint(acc[1]) << 32) | __float_as_uint(acc[0]);
  u64 b = ((u64)__float_as_uint(acc[3]) << 32) | __float_as_uint(acc[2]);
  __hip_atomic_store(&P8[2*idx],     a, __ATOMIC_RELAXED, __HIP_MEMORY_SCOPE_AGENT);
  __hip_atomic_store(&P8[2*idx + 1], b, __ATOMIC_RELAXED, __HIP_MEMORY_SCOPE_AGENT);
}

// Combine partials: 128 WGs (wave 0 only), write dout + next input planes.
__device__ __forceinline__ void mlp_combine(
    const float* __restrict__ Part, const float* __restrict__ mb,
    float* __restrict__ dout,
    ushort_t* __restrict__ inph, ushort_t* __restrict__ inpl, int wg, int t)
{
  if (threadIdx.x >= 64) return;
  const int lane = threadIdx.x;
  const int d0 = (wg >> 3)*16, b0 = (wg & 7)*16;
  const int cb = lane >> 4, fr = lane & 15;
  const u64* P8 = (const u64*)Part;
  f32x4 s = {};
#pragma unroll
  for (int kh = 0; kh < 2; ++kh)
#pragma unroll
    for (int wv = 0; wv < 4; ++wv){
      const size_t idx = (((size_t)wg*2 + kh)*4 + wv)*64 + lane;
      u64 a = __hip_atomic_load(&P8[2*idx],     __ATOMIC_RELAXED, __HIP_MEMORY_SCOPE_AGENT);
      u64 b = __hip_atomic_load(&P8[2*idx + 1], __ATOMIC_RELAXED, __HIP_MEMORY_SCOPE_AGENT);
      s[0] += __uint_as_float((unsigned)a);
      s[1] += __uint_as_float((unsigned)(a >> 32));
      s[2] += __uint_as_float((unsigned)b);
      s[3] += __uint_as_float((unsigned)(b >> 32));
    }
  const int dr = d0 + cb*4, b = b0 + fr;
  s += *(const f32x4*)&mb[dr];
  *(f32x4*)&dout[((size_t)b*128 + t)*256 + dr] = s;
  u16x4 hv, lv;
#pragma unroll
  for (int j = 0; j < 4; ++j){
    hv[j] = f2bf(s[j]);
    lv[j] = f2bf(s[j] - bf2f(hv[j]));
  }
  union { u16x4 v; u64 u; } ch, cl; ch.v = hv; cl.v = lv;
  __hip_atomic_store((u64*)&inph[(size_t)b*256 + dr], ch.u, __ATOMIC_RELAXED, __HIP_MEMORY_SCOPE_AGENT);
  __hip_atomic_store((u64*)&inpl[(size_t)b*256 + dr], cl.u, __ATOMIC_RELAXED, __HIP_MEMORY_SCOPE_AGENT);
}

// WG -> (dir, rowgroup, b-half); b-halves 8 apart => same XCD (round-robin).
__device__ __forceinline__ void wg_decode(int wg, int& dir, int& r0, int& n0,
                                          int& b0, int& me){
  const int half = (wg >> 3) & 1;
  const int rgd  = (wg & 7) | ((wg >> 4) << 3);        // 0..127
  dir = rgd >> 6;
  const int rg = rgd & 63;
  r0 = rg * 64; n0 = rg * 16; b0 = half * 64;
  me = (rg << 1) | half;                               // 0..127 within dir
}

__global__ void __launch_bounds__(256) rnn_enc_kernel(
    const float* __restrict__ Wih_f, const float* __restrict__ b_f,
    const float* __restrict__ Wih_b, const float* __restrict__ b_b,
    const ushort_t* __restrict__ WhhH, const ushort_t* __restrict__ WhhL,
    const float* __restrict__ x,
    ushort_t* __restrict__ Hh, ushort_t* __restrict__ Hl,
    float* __restrict__ C, unsigned* flagsE)
{
  extern __shared__ ushort_t LDS[];
  int dir, r0, n0, b0, me;
  wg_decode(blockIdx.x, dir, r0, n0, b0, me);
  const float* Wih = dir ? Wih_b : Wih_f;
  const float* bia = dir ? b_b : b_f;
  const ushort_t* WhH = WhhH + (size_t)dir*4096*1024;
  const ushort_t* WhL = WhhL + (size_t)dir*4096*1024;
  unsigned* fl = flagsE + dir*128;
  float creg[2][2] = {{0.f, 0.f}, {0.f, 0.f}};
  unsigned gen = 0;
  for (int t = 0; t < 256; ++t){
    const int tt = dir ? (255 - t) : t;
    const int rp = t & 1;
    cell_step<1>(Wih, WhH, WhL, bia,
                 x + (size_t)tt*256, nullptr, nullptr,
                 Hh + (size_t)rp     *262144 + dir*1024,
                 Hl + (size_t)rp     *262144 + dir*1024,
                 Hh + (size_t)(rp^1) *262144 + dir*1024,
                 Hl + (size_t)(rp^1) *262144 + dir*1024,
                 creg, r0, n0, b0, LDS);
    ++gen;
    bar(fl, 128, me, gen);
  }
  // hand off c-state to decoder (cross-kernel boundary flushes)
  {
    const int lane = threadIdx.x & 63, wv = threadIdx.x >> 6;
    const int wm = wv >> 1, wn = wv & 1, cb = lane >> 4, fr = lane & 15;
    float* Cst = C + (size_t)dir*1024*128;
#pragma unroll
    for (int m = 0; m < 2; ++m)
#pragma unroll
      for (int nb = 0; nb < 2; ++nb){
        const int n = n0 + wm*8 + m*4 + cb;
        const int b = b0 + wn*32 + nb*16 + fr;
        Cst[n*128 + b] = creg[m][nb];
      }
  }
}

__global__ void __launch_bounds__(256) rnn_dec_kernel(
    const float* __restrict__ Wih_f, const float* __restrict__ b_f,
    const float* __restrict__ Wih_b, const float* __restrict__ b_b,
    const ushort_t* __restrict__ WhhH, const ushort_t* __restrict__ WhhL,
    const ushort_t* __restrict__ mWh, const ushort_t* __restrict__ mWl,
    const float* __restrict__ mb,
    ushort_t* __restrict__ Hh, ushort_t* __restrict__ Hl,
    float* __restrict__ C,
    ushort_t* __restrict__ inph, ushort_t* __restrict__ inpl,
    float* __restrict__ Part,
    float* __restrict__ dout, unsigned* flagsD)
{
  extern __shared__ ushort_t LDS[];
  const int wg = blockIdx.x;
  int dir, r0, n0, b0, me;
  wg_decode(wg, dir, r0, n0, b0, me);
  const float* Wih = dir ? Wih_b : Wih_f;
  const float* bia = dir ? b_b : b_f;
  const ushort_t* WhH = WhhH + (size_t)dir*4096*1024;
  const ushort_t* WhL = WhhL + (size_t)dir*4096*1024;
  float creg[2][2];
  {
    const int lane = threadIdx.x & 63, wv = threadIdx.x >> 6;
    const int wm = wv >> 1, wn = wv & 1, cb = lane >> 4, fr = lane & 15;
    const float* Cst = C + (size_t)dir*1024*128;
#pragma unroll
    for (int m = 0; m < 2; ++m)
#pragma unroll
      for (int nb = 0; nb < 2; ++nb){
        const int n = n0 + wm*8 + m*4 + cb;
        const int b = b0 + wn*32 + nb*16 + fr;
        creg[m][nb] = Cst[n*128 + b];
      }
  }
  for (int t = 0; t < 128; ++t){
    const int rp = t & 1;
    cell_step<0>(Wih, WhH, WhL, bia,
                 nullptr, inph, inpl,
                 Hh + (size_t)rp     *262144 + dir*1024,
                 Hl + (size_t)rp     *262144 + dir*1024,
                 Hh + (size_t)(rp^1) *262144 + dir*1024,
                 Hl + (size_t)(rp^1) *262144 + dir*1024,
                 creg, r0, n0, b0, LDS);
    bar(flagsD, 256, wg, (unsigned)(3*t + 1));
    mlp_gemm(Hh + (size_t)(rp^1)*262144, Hl + (size_t)(rp^1)*262144,
             mWh, mWl, Part, wg, LDS);
    bar(flagsD, 256, wg, (unsigned)(3*t + 2));
    if (wg < 128) mlp_combine(Part, mb, dout, inph, inpl, wg, t);
    bar(flagsD, 256, wg, (unsigned)(3*t + 3));
  }
}

// ---------------------------------------------------------------------------
// Prep kernels
// ---------------------------------------------------------------------------
__global__ void k_wplanes(ushort_t* Hp, ushort_t* Lp,
                          const float* Whh_f, const float* Whh_b)
{
  const size_t N = 2ull*4096*1024;
  for (size_t i = (size_t)blockIdx.x*blockDim.x + threadIdx.x; i < N;
       i += (size_t)gridDim.x*blockDim.x){
    int dir = (int)(i >> 22);
    int r   = (int)((i >> 10) & 4095);
    int k   = (int)(i & 1023);
    int n = r >> 2, q = r & 3;
    const float* W = dir ? Whh_b : Whh_f;
    float v = W[(size_t)(q*1024 + n)*1024 + k];
    unsigned short h = f2bf(v);
    Hp[i] = h;
    Lp[i] = f2bf(v - bf2f(h));
  }
}

__global__ void k_init(ushort_t* Hh, ushort_t* Hl,
                       ushort_t* inph, ushort_t* inpl,
                       ushort_t* mWh, ushort_t* mWl,
                       const float* x, const float* mW, unsigned* cnt)
{
  const size_t N = 524288;  // 2 parity * 128 * 2048 == 256*2048 (mlp)
  for (size_t i = (size_t)blockIdx.x*blockDim.x + threadIdx.x; i < N;
       i += (size_t)gridDim.x*blockDim.x){
    Hh[i] = 0; Hl[i] = 0;
    float wv = mW[i];
    unsigned short wh = f2bf(wv);
    mWh[i] = wh;
    mWl[i] = f2bf(wv - bf2f(wh));
    if (i < 32768){
      int b = (int)(i >> 8), d = (int)(i & 255);
      float v = x[((size_t)b*256 + 255)*256 + d];        // x[:, 255, :]
      unsigned short hi = f2bf(v);
      inph[i] = hi;
      inpl[i] = f2bf(v - bf2f(hi));
    }
    if (i < 1024) cnt[i] = 0;
  }
}

// ---------------------------------------------------------------------------
extern "C" void kernel_launch(void* const* d_in, const int* in_sizes, int n_in,
                              void* d_out, int out_size, void* d_ws, size_t ws_size,
                              hipStream_t stream)
{
  (void)in_sizes; (void)n_in; (void)out_size; (void)ws_size;
  const float* x      = (const float*)d_in[0];
  const float* eWih_f = (const float*)d_in[2];
  const float* eWhh_f = (const float*)d_in[3];
  const float* eb_f   = (const float*)d_in[4];
  const float* eWih_b = (const float*)d_in[5];
  const float* eWhh_b = (const float*)d_in[6];
  const float* eb_b   = (const float*)d_in[7];
  const float* dWih_f = (const float*)d_in[8];
  const float* dWhh_f = (const float*)d_in[9];
  const float* db_f   = (const float*)d_in[10];
  const float* dWih_b = (const float*)d_in[11];
  const float* dWhh_b = (const float*)d_in[12];
  const float* db_b   = (const float*)d_in[13];
  const float* mW     = (const float*)d_in[14];
  const float* mb     = (const float*)d_in[15];

  char* p = (char*)d_ws;
  size_t off = 0;
  unsigned* cnt   = (unsigned*)(p + off);  off += 4096;      // flagsD[256], flagsE[256]
  ushort_t* WhhEh = (ushort_t*)(p + off);  off += 16777216;
  ushort_t* WhhEl = (ushort_t*)(p + off);  off += 16777216;
  ushort_t* WhhDh = (ushort_t*)(p + off);  off += 16777216;
  ushort_t* WhhDl = (ushort_t*)(p + off);  off += 16777216;
  ushort_t* mWh   = (ushort_t*)(p + off);  off += 1048576;
  ushort_t* mWl   = (ushort_t*)(p + off);  off += 1048576;
  ushort_t* Hh    = (ushort_t*)(p + off);  off += 1048576;
  ushort_t* Hl    = (ushort_t*)(p + off);  off += 1048576;
  float*    C     = (float*)(p + off);     off += 1048576;
  ushort_t* inph  = (ushort_t*)(p + off);  off += 65536;
  ushort_t* inpl  = (ushort_t*)(p + off);  off += 65536;
  float*    Part  = (float*)(p + off);     off += 1048576;   // 128*2*4*64 f32x4

  unsigned* flagsD = cnt;
  unsigned* flagsE = cnt + 256;

  hipFuncSetAttribute(reinterpret_cast<const void*>(rnn_enc_kernel),
                      hipFuncAttributeMaxDynamicSharedMemorySize, 131072);
  hipFuncSetAttribute(reinterpret_cast<const void*>(rnn_dec_kernel),
                      hipFuncAttributeMaxDynamicSharedMemorySize, 131072);

  k_init   <<<512, 256, 0, stream>>>(Hh, Hl, inph, inpl, mWh, mWl, x, mW, cnt);
  k_wplanes<<<2048, 256, 0, stream>>>(WhhEh, WhhEl, eWhh_f, eWhh_b);
  k_wplanes<<<2048, 256, 0, stream>>>(WhhDh, WhhDl, dWhh_f, dWhh_b);

  rnn_enc_kernel<<<NWG, 256, 131072, stream>>>(eWih_f, eb_f, eWih_b, eb_b,
                                               WhhEh, WhhEl, x, Hh, Hl, C, flagsE);
  rnn_dec_kernel<<<NWG, 256, 131072, stream>>>(dWih_f, db_f, dWih_b, db_b,
                                               WhhDh, WhhDl, mWh, mWl, mb,
                                               Hh, Hl, C, inph, inpl, Part,
                                               (float*)d_out, flagsD);
}